// Round 1
// baseline (702.474 us; speedup 1.0000x reference)
//
#include <hip/hip_runtime.h>
#include <hip/hip_bf16.h>
#include <math.h>

#define BATCH 8
#define CFULL 256
#define HEADS 8
#define CH 32
#define NTOK 16384
#define TN 64
#define BPB 64
#define TPB 4
#define EPS 1e-6f

typedef __bf16 bf16x8 __attribute__((ext_vector_type(8)));
typedef float f32x4 __attribute__((ext_vector_type(4)));
typedef float f32x16 __attribute__((ext_vector_type(16)));

__device__ __forceinline__ unsigned short bf16bits(float f) {
    return __builtin_bit_cast(unsigned short, (__bf16)f);
}
__device__ __forceinline__ float softplus_f(float x) {
    return fmaxf(x, 0.0f) + log1pf(__expf(-fabsf(x)));
}

// Convert the three weight matrices to bf16 once per launch.
__global__ void prep_w(const float* __restrict__ Wq, const float* __restrict__ Wk,
                       const float* __restrict__ Wv, unsigned short* __restrict__ dst)
{
    const int i = blockIdx.x * 256 + threadIdx.x;
    const float* src = (i < 65536) ? Wq : ((i < 131072) ? Wk : Wv);
    dst[i] = bf16bits(src[i & 65535]);
}

// ---------------------------------------------------------------------------
// Kernel 1: per (b, token-range) compute k = softplus(Wk x + bk), v = Wv x + bv
// and accumulate kv[b,p,m,c] = sum_n k[m,n] v[c,n], ksum[b,ch] = sum_n k[ch,n].
// ---------------------------------------------------------------------------
__global__ __launch_bounds__(256, 2)
void k1_kv(const float* __restrict__ x,
           const unsigned short* __restrict__ Wk,
           const unsigned short* __restrict__ Wv,
           const float* __restrict__ bk, const float* __restrict__ bv,
           float* __restrict__ kvws, float* __restrict__ ksws)
{
    // xs: staged x tile, element (tok, ch) at tok*256 + (ch ^ ((tok&7)<<3))  [bf16]
    //     later reused as vs: element (och, tok) at och*64 + (tok ^ ((och&7)<<3))
    __shared__ __align__(16) unsigned short xs[TN * CFULL];
    __shared__ __align__(16) unsigned short ks[CFULL * TN];
    __shared__ float bkl[CFULL];
    __shared__ float bvl[CFULL];

    const int tid = threadIdx.x;
    const int lane = tid & 63;
    const int wv = tid >> 6;          // wave 0..3 -> och rows [wv*64, wv*64+64)
    const int l15 = lane & 15;
    const int lhi = lane >> 4;        // 0..3
    const int b = blockIdx.x / BPB;
    const int blk = blockIdx.x % BPB;
    const float* xb = x + (size_t)b * CFULL * NTOK;

    bkl[tid] = bk[tid];
    bvl[tid] = bv[tid];

    f32x16 kvacc0 = {};               // head 2*wv
    f32x16 kvacc1 = {};               // head 2*wv+1
    float ksum[4] = {0.f, 0.f, 0.f, 0.f};

    for (int t = 0; t < TPB; ++t) {
        const int n0 = (blk * TPB + t) * TN;
        __syncthreads();              // prev tile fully consumed
        // ---- stage x tile -> xs (bf16, transposed, swizzled)
        {
            const int ch0 = (tid & 127) * 2;
            const int th = (tid >> 7) * 32;
            const float* s0 = xb + (size_t)ch0 * NTOK + n0 + th;
            const float* s1 = s0 + NTOK;
            #pragma unroll
            for (int g = 0; g < 8; ++g) {
                const float4 a = *(const float4*)(s0 + g * 4);
                const float4 c = *(const float4*)(s1 + g * 4);
                #pragma unroll
                for (int i = 0; i < 4; ++i) {
                    const int tok = th + g * 4 + i;
                    const unsigned int u = (unsigned int)bf16bits((&a.x)[i]) |
                                           ((unsigned int)bf16bits((&c.x)[i]) << 16);
                    *(unsigned int*)&xs[tok * CFULL + (ch0 ^ ((tok & 7) << 3))] = u;
                }
            }
        }
        __syncthreads();

        // ---- K projection (transposed: D[tok][och]) + softplus -> ks
        {
            f32x4 acc[4][4] = {};
            #pragma unroll
            for (int kk = 0; kk < 8; ++kk) {
                const int ch0 = kk * 32 + lhi * 8;
                bf16x8 af[4], bfr[4];
                #pragma unroll
                for (int tf = 0; tf < 4; ++tf) {
                    const int tok = tf * 16 + l15;
                    af[tf] = *(const bf16x8*)&xs[tok * CFULL + (ch0 ^ ((tok & 7) << 3))];
                }
                #pragma unroll
                for (int of = 0; of < 4; ++of) {
                    const int och = wv * 64 + of * 16 + l15;
                    bfr[of] = *(const bf16x8*)&Wk[och * CFULL + ch0];
                }
                #pragma unroll
                for (int tf = 0; tf < 4; ++tf)
                    #pragma unroll
                    for (int of = 0; of < 4; ++of)
                        acc[tf][of] = __builtin_amdgcn_mfma_f32_16x16x32_bf16(af[tf], bfr[of], acc[tf][of], 0, 0, 0);
            }
            #pragma unroll
            for (int tf = 0; tf < 4; ++tf) {
                #pragma unroll
                for (int of = 0; of < 4; ++of) {
                    const int och = wv * 64 + of * 16 + l15;
                    const float bias = bkl[och];
                    ushort4 pk;
                    float v0 = softplus_f(acc[tf][of][0] + bias);
                    float v1 = softplus_f(acc[tf][of][1] + bias);
                    float v2 = softplus_f(acc[tf][of][2] + bias);
                    float v3 = softplus_f(acc[tf][of][3] + bias);
                    ksum[of] += v0 + v1 + v2 + v3;
                    pk.x = bf16bits(v0); pk.y = bf16bits(v1);
                    pk.z = bf16bits(v2); pk.w = bf16bits(v3);
                    const int tok0 = tf * 16 + lhi * 4;
                    *(ushort4*)&ks[och * TN + (tok0 ^ ((och & 7) << 3))] = pk;
                }
            }
        }

        // ---- V projection (transposed), keep packed in registers
        ushort4 vpk[4][4];
        {
            f32x4 acc[4][4] = {};
            #pragma unroll
            for (int kk = 0; kk < 8; ++kk) {
                const int ch0 = kk * 32 + lhi * 8;
                bf16x8 af[4], bfr[4];
                #pragma unroll
                for (int tf = 0; tf < 4; ++tf) {
                    const int tok = tf * 16 + l15;
                    af[tf] = *(const bf16x8*)&xs[tok * CFULL + (ch0 ^ ((tok & 7) << 3))];
                }
                #pragma unroll
                for (int of = 0; of < 4; ++of) {
                    const int och = wv * 64 + of * 16 + l15;
                    bfr[of] = *(const bf16x8*)&Wv[och * CFULL + ch0];
                }
                #pragma unroll
                for (int tf = 0; tf < 4; ++tf)
                    #pragma unroll
                    for (int of = 0; of < 4; ++of)
                        acc[tf][of] = __builtin_amdgcn_mfma_f32_16x16x32_bf16(af[tf], bfr[of], acc[tf][of], 0, 0, 0);
            }
            #pragma unroll
            for (int tf = 0; tf < 4; ++tf) {
                #pragma unroll
                for (int of = 0; of < 4; ++of) {
                    const int och = wv * 64 + of * 16 + l15;
                    const float bias = bvl[och];
                    vpk[tf][of].x = bf16bits(acc[tf][of][0] + bias);
                    vpk[tf][of].y = bf16bits(acc[tf][of][1] + bias);
                    vpk[tf][of].z = bf16bits(acc[tf][of][2] + bias);
                    vpk[tf][of].w = bf16bits(acc[tf][of][3] + bias);
                }
            }
        }
        __syncthreads();              // everyone done reading xs
        #pragma unroll
        for (int tf = 0; tf < 4; ++tf)
            #pragma unroll
            for (int of = 0; of < 4; ++of) {
                const int och = wv * 64 + of * 16 + l15;
                const int tok0 = tf * 16 + lhi * 4;
                *(ushort4*)&xs[och * TN + (tok0 ^ ((och & 7) << 3))] = vpk[tf][of];
            }
        __syncthreads();

        // ---- kv accumulation: per head, kv[m][c] += sum_tok k[m][tok] v[c][tok]
        {
            const int l31 = lane & 31;
            const int tb = (lane >> 5) * 8;
            #pragma unroll
            for (int h = 0; h < 2; ++h) {
                const int row = (wv * 2 + h) * CH + l31;
                f32x16& kva = h ? kvacc1 : kvacc0;
                #pragma unroll
                for (int ts = 0; ts < 4; ++ts) {
                    const int sw = (ts * 16 + tb) ^ ((row & 7) << 3);
                    bf16x8 ak = *(const bf16x8*)&ks[row * TN + sw];
                    bf16x8 av = *(const bf16x8*)&xs[row * TN + sw];
                    kva = __builtin_amdgcn_mfma_f32_32x32x16_bf16(ak, av, kva, 0, 0, 0);
                }
            }
        }
    }

    // ---- epilogue: ksum (reduce over token lane-groups) + kv atomics
    #pragma unroll
    for (int of = 0; of < 4; ++of) {
        float v = ksum[of];
        v += __shfl_xor(v, 16);
        v += __shfl_xor(v, 32);
        if (lhi == 0) atomicAdd(&ksws[b * CFULL + wv * 64 + of * 16 + l15], v);
    }
    {
        const int l31 = lane & 31;
        #pragma unroll
        for (int h = 0; h < 2; ++h) {
            const int p = wv * 2 + h;
            const f32x16& kva = h ? kvacc1 : kvacc0;
            #pragma unroll
            for (int r = 0; r < 16; ++r) {
                const int m = (r & 3) + 8 * (r >> 2) + 4 * (lane >> 5);
                atomicAdd(&kvws[((b * HEADS + p) * CH + m) * CH + l31], kva[r]);
            }
        }
    }
}

// ---------------------------------------------------------------------------
// Kernel 2: q = softplus(Wq x + bq); out[c,n] = sum_m kv[m,c] q[m,n] / (q . (ksum+eps))
// ---------------------------------------------------------------------------
__global__ __launch_bounds__(256, 2)
void k2_out(const float* __restrict__ x,
            const unsigned short* __restrict__ Wq,
            const float* __restrict__ bq,
            const float* __restrict__ kvws, const float* __restrict__ ksws,
            float* __restrict__ outp)
{
    __shared__ __align__(16) unsigned short xs[TN * CFULL];   // staged x; later qs[tok][och]
    __shared__ __align__(16) unsigned short kvT[HEADS * CH * CH]; // [p][c][m] bf16
    __shared__ float kse[CFULL];
    __shared__ float bql[CFULL];
    __shared__ float normls[HEADS][TN];

    const int tid = threadIdx.x;
    const int lane = tid & 63;
    const int wv = tid >> 6;
    const int l15 = lane & 15;
    const int lhi = lane >> 4;
    const int b = blockIdx.x / BPB;
    const int blk = blockIdx.x % BPB;
    const float* xb = x + (size_t)b * CFULL * NTOK;
    float* ob = outp + (size_t)b * CFULL * NTOK;

    bql[tid] = bq[tid];
    kse[tid] = ksws[b * CFULL + tid] + EPS;
    for (int i = tid; i < HEADS * CH * CH; i += 256) {
        const int p = i >> 10, c = (i >> 5) & 31, m = i & 31;
        kvT[i] = bf16bits(kvws[((b * HEADS + p) * CH + m) * CH + c]);
    }

    for (int t = 0; t < TPB; ++t) {
        const int n0 = (blk * TPB + t) * TN;
        __syncthreads();
        // ---- stage x tile (same as k1)
        {
            const int ch0 = (tid & 127) * 2;
            const int th = (tid >> 7) * 32;
            const float* s0 = xb + (size_t)ch0 * NTOK + n0 + th;
            const float* s1 = s0 + NTOK;
            #pragma unroll
            for (int g = 0; g < 8; ++g) {
                const float4 a = *(const float4*)(s0 + g * 4);
                const float4 c = *(const float4*)(s1 + g * 4);
                #pragma unroll
                for (int i = 0; i < 4; ++i) {
                    const int tok = th + g * 4 + i;
                    const unsigned int u = (unsigned int)bf16bits((&a.x)[i]) |
                                           ((unsigned int)bf16bits((&c.x)[i]) << 16);
                    *(unsigned int*)&xs[tok * CFULL + (ch0 ^ ((tok & 7) << 3))] = u;
                }
            }
        }
        __syncthreads();

        // ---- Q projection (original orientation: D[och][tok])
        ushort4 qpk[4][4];
        {
            f32x4 acc[4][4] = {};
            #pragma unroll
            for (int kk = 0; kk < 8; ++kk) {
                const int ch0 = kk * 32 + lhi * 8;
                bf16x8 aw[4], bx[4];
                #pragma unroll
                for (int mf = 0; mf < 4; ++mf)
                    aw[mf] = *(const bf16x8*)&Wq[(wv * 64 + mf * 16 + l15) * CFULL + ch0];
                #pragma unroll
                for (int nf = 0; nf < 4; ++nf) {
                    const int tok = nf * 16 + l15;
                    bx[nf] = *(const bf16x8*)&xs[tok * CFULL + (ch0 ^ ((tok & 7) << 3))];
                }
                #pragma unroll
                for (int mf = 0; mf < 4; ++mf)
                    #pragma unroll
                    for (int nf = 0; nf < 4; ++nf)
                        acc[mf][nf] = __builtin_amdgcn_mfma_f32_16x16x32_bf16(aw[mf], bx[nf], acc[mf][nf], 0, 0, 0);
            }
            #pragma unroll
            for (int mf = 0; mf < 4; ++mf) {
                #pragma unroll
                for (int nf = 0; nf < 4; ++nf) {
                    const int och0 = wv * 64 + mf * 16 + lhi * 4;
                    qpk[mf][nf].x = bf16bits(softplus_f(acc[mf][nf][0] + bql[och0 + 0]));
                    qpk[mf][nf].y = bf16bits(softplus_f(acc[mf][nf][1] + bql[och0 + 1]));
                    qpk[mf][nf].z = bf16bits(softplus_f(acc[mf][nf][2] + bql[och0 + 2]));
                    qpk[mf][nf].w = bf16bits(softplus_f(acc[mf][nf][3] + bql[och0 + 3]));
                }
            }
        }
        __syncthreads();              // everyone done reading xs
        // write qs[tok][och] into xs region (4 consecutive och per lane)
        #pragma unroll
        for (int mf = 0; mf < 4; ++mf)
            #pragma unroll
            for (int nf = 0; nf < 4; ++nf) {
                const int tok = nf * 16 + l15;
                const int och0 = wv * 64 + mf * 16 + lhi * 4;
                *(ushort4*)&xs[tok * CFULL + (och0 ^ ((tok & 7) << 3))] = qpk[mf][nf];
            }
        __syncthreads();

        // ---- denominators: lane handles tok = lane for its wave's 2 heads
        #pragma unroll
        for (int h = 0; h < 2; ++h) {
            const int p = wv * 2 + h;
            float d = 0.f;
            #pragma unroll
            for (int mg = 0; mg < 4; ++mg) {
                bf16x8 qv = *(const bf16x8*)&xs[lane * CFULL + ((p * 32 + mg * 8) ^ ((lane & 7) << 3))];
                #pragma unroll
                for (int j = 0; j < 8; ++j)
                    d += (float)qv[j] * kse[p * 32 + mg * 8 + j];
            }
            normls[p][lane] = 1.0f / d;
        }
        __syncthreads();

        // ---- PV: D[c][tok] = sum_m kvT[c][m] q[m][tok]; scale by norm; store
        #pragma unroll
        for (int h = 0; h < 2; ++h) {
            const int p = wv * 2 + h;
            bf16x8 akv0 = *(const bf16x8*)&kvT[p * 1024 + l15 * 32 + lhi * 8];
            bf16x8 akv1 = *(const bf16x8*)&kvT[p * 1024 + (16 + l15) * 32 + lhi * 8];
            #pragma unroll
            for (int nf = 0; nf < 4; ++nf) {
                const int tok = nf * 16 + l15;
                bf16x8 bqf = *(const bf16x8*)&xs[tok * CFULL + ((p * 32 + lhi * 8) ^ ((tok & 7) << 3))];
                const float nrm = normls[p][tok];
                f32x4 o0 = {}, o1 = {};
                o0 = __builtin_amdgcn_mfma_f32_16x16x32_bf16(akv0, bqf, o0, 0, 0, 0);
                o1 = __builtin_amdgcn_mfma_f32_16x16x32_bf16(akv1, bqf, o1, 0, 0, 0);
                const int och0 = p * 32 + lhi * 4;
                #pragma unroll
                for (int r = 0; r < 4; ++r) {
                    ob[(size_t)(och0 + r) * NTOK + n0 + tok] = o0[r] * nrm;
                    ob[(size_t)(och0 + 16 + r) * NTOK + n0 + tok] = o1[r] * nrm;
                }
            }
        }
    }
}

extern "C" void kernel_launch(void* const* d_in, const int* in_sizes, int n_in,
                              void* d_out, int out_size, void* d_ws, size_t ws_size,
                              hipStream_t stream)
{
    const float* x  = (const float*)d_in[0];
    const float* Wq = (const float*)d_in[1];
    const float* bq = (const float*)d_in[2];
    const float* Wk = (const float*)d_in[3];
    const float* bk = (const float*)d_in[4];
    const float* Wv = (const float*)d_in[5];
    const float* bv = (const float*)d_in[6];
    float* out = (float*)d_out;

    unsigned short* wbf = (unsigned short*)d_ws;                        // 3 * 65536 bf16
    float* kvws = (float*)((char*)d_ws + (size_t)3 * 65536 * 2);        // [8][8][32][32]
    float* ksws = kvws + BATCH * HEADS * CH * CH;                       // [8][256]

    hipMemsetAsync(kvws, 0, (BATCH * HEADS * CH * CH + BATCH * CFULL) * sizeof(float), stream);
    hipLaunchKernelGGL(prep_w, dim3(768), dim3(256), 0, stream, Wq, Wk, Wv, wbf);
    hipLaunchKernelGGL(k1_kv, dim3(BATCH * BPB), dim3(256), 0, stream,
                       x, wbf + 65536, wbf + 2 * 65536, bk, bv, kvws, ksws);
    hipLaunchKernelGGL(k2_out, dim3(BATCH * BPB), dim3(256), 0, stream,
                       x, wbf, bq, kvws, ksws, out);
}

// Round 2
// 570.387 us; speedup vs baseline: 1.2316x; 1.2316x over previous
//
#include <hip/hip_runtime.h>
#include <hip/hip_bf16.h>
#include <math.h>

#define BATCH 8
#define CFULL 256
#define HEADS 8
#define CH 32
#define NTOK 16384
#define TN 64
#define K1_BPB 64
#define K1_TPB 4
#define EPS 1e-6f

// xs tile swizzle: channel-index XOR spreads banks; bits>=3 so 4/8-short chunks stay intact
#define SWZ(tok) ((((tok) & 7) << 3) ^ ((((tok) >> 3) & 3) << 6))

typedef __bf16 bf16x8 __attribute__((ext_vector_type(8)));
typedef float f32x4 __attribute__((ext_vector_type(4)));
typedef float f32x16 __attribute__((ext_vector_type(16)));

__device__ __forceinline__ unsigned short bf16bits(float f) {
    return __builtin_bit_cast(unsigned short, (__bf16)f);
}
__device__ __forceinline__ float softplus_f(float x) {
    return fmaxf(x, 0.0f) + log1pf(__expf(-fabsf(x)));
}

// 4x4 transpose within a quad of lanes. In: lane q=lane&3 holds row q (4 consecutive
// row-elements). Out: lane q holds column q (the 4 rows' q-th elements, in order).
__device__ __forceinline__ void quad_transpose(float4& a, int lane) {
    const bool o1 = lane & 1, o2 = lane & 2;
    float s1 = o1 ? a.x : a.y; float g1 = __shfl_xor(s1, 1);
    float s2 = o1 ? a.z : a.w; float g2 = __shfl_xor(s2, 1);
    a.x = o1 ? g1 : a.x;  a.y = o1 ? a.y : g1;
    a.z = o1 ? g2 : a.z;  a.w = o1 ? a.w : g2;
    float s3 = o2 ? a.x : a.z; float g3 = __shfl_xor(s3, 2);
    float s4 = o2 ? a.y : a.w; float g4 = __shfl_xor(s4, 2);
    a.x = o2 ? g3 : a.x;  a.z = o2 ? a.z : g3;
    a.y = o2 ? g4 : a.y;  a.w = o2 ? a.w : g4;
}

// Stage one 64-token x tile into xs (tok-major bf16, SWZ swizzled).
// Wave wv covers channel rows [wv*64, wv*64+64). Fully coalesced: each wave
// instruction reads 4 rows x 256B contiguous.
__device__ __forceinline__ void stage_x(const float* __restrict__ xb, int n0,
                                        unsigned short* xs, int wv, int lane) {
    const int q4 = lane & 3;
    const int t0 = (lane >> 2) << 2;
    #pragma unroll
    for (int g = 0; g < 16; ++g) {
        const int c0 = wv * 64 + g * 4;
        float4 a = *(const float4*)(xb + (size_t)(c0 + q4) * NTOK + n0 + t0);
        quad_transpose(a, lane);
        // now this lane holds channels c0..c0+3 of token == lane
        ushort4 pk;
        pk.x = bf16bits(a.x); pk.y = bf16bits(a.y);
        pk.z = bf16bits(a.z); pk.w = bf16bits(a.w);
        *(ushort4*)&xs[lane * CFULL + (c0 ^ SWZ(lane))] = pk;
    }
}

// Convert the three weight matrices to bf16 once per launch.
__global__ void prep_w(const float* __restrict__ Wq, const float* __restrict__ Wk,
                       const float* __restrict__ Wv, unsigned short* __restrict__ dst)
{
    const int i = blockIdx.x * 256 + threadIdx.x;
    const float* src = (i < 65536) ? Wq : ((i < 131072) ? Wk : Wv);
    dst[i] = bf16bits(src[i & 65535]);
}

// ---------------------------------------------------------------------------
// Kernel 1: k = softplus(Wk x + bk), v = Wv x + bv;
// kv[b,p,m,c] += sum_n k[m,n] v[c,n]; ksum[b,ch] += sum_n k[ch,n].
// ---------------------------------------------------------------------------
__global__ __launch_bounds__(256, 2)
void k1_kv(const float* __restrict__ x,
           const unsigned short* __restrict__ Wk,
           const unsigned short* __restrict__ Wv,
           const float* __restrict__ bk, const float* __restrict__ bv,
           float* __restrict__ kvws, float* __restrict__ ksws)
{
    __shared__ __align__(16) unsigned short xs[TN * CFULL]; // staged x; later vs[och][tok]
    __shared__ __align__(16) unsigned short ks[CFULL * TN]; // k, och-major
    __shared__ float bkl[CFULL];
    __shared__ float bvl[CFULL];

    const int tid = threadIdx.x;
    const int lane = tid & 63;
    const int wv = tid >> 6;
    const int l15 = lane & 15;
    const int lhi = lane >> 4;
    const int b = blockIdx.x / K1_BPB;
    const int blk = blockIdx.x % K1_BPB;
    const float* xb = x + (size_t)b * CFULL * NTOK;

    bkl[tid] = bk[tid];
    bvl[tid] = bv[tid];

    f32x16 kvacc0 = {};
    f32x16 kvacc1 = {};
    float ksum[4] = {0.f, 0.f, 0.f, 0.f};

    for (int t = 0; t < K1_TPB; ++t) {
        const int n0 = (blk * K1_TPB + t) * TN;
        __syncthreads();              // prev tile fully consumed
        stage_x(xb, n0, xs, wv, lane);
        __syncthreads();

        // ---- K projection (D[tok][och]) + softplus -> ks
        {
            f32x4 acc[4][4] = {};
            #pragma unroll
            for (int kk = 0; kk < 8; ++kk) {
                const int ch0 = kk * 32 + lhi * 8;
                bf16x8 af[4], bfr[4];
                #pragma unroll
                for (int tf = 0; tf < 4; ++tf) {
                    const int tok = tf * 16 + l15;
                    af[tf] = *(const bf16x8*)&xs[tok * CFULL + (ch0 ^ SWZ(tok))];
                }
                #pragma unroll
                for (int of = 0; of < 4; ++of) {
                    const int och = wv * 64 + of * 16 + l15;
                    bfr[of] = *(const bf16x8*)&Wk[och * CFULL + ch0];
                }
                #pragma unroll
                for (int tf = 0; tf < 4; ++tf)
                    #pragma unroll
                    for (int of = 0; of < 4; ++of)
                        acc[tf][of] = __builtin_amdgcn_mfma_f32_16x16x32_bf16(af[tf], bfr[of], acc[tf][of], 0, 0, 0);
            }
            #pragma unroll
            for (int tf = 0; tf < 4; ++tf) {
                #pragma unroll
                for (int of = 0; of < 4; ++of) {
                    const int och = wv * 64 + of * 16 + l15;
                    const float bias = bkl[och];
                    float v0 = softplus_f(acc[tf][of][0] + bias);
                    float v1 = softplus_f(acc[tf][of][1] + bias);
                    float v2 = softplus_f(acc[tf][of][2] + bias);
                    float v3 = softplus_f(acc[tf][of][3] + bias);
                    ksum[of] += v0 + v1 + v2 + v3;
                    ushort4 pk;
                    pk.x = bf16bits(v0); pk.y = bf16bits(v1);
                    pk.z = bf16bits(v2); pk.w = bf16bits(v3);
                    const int tok0 = tf * 16 + lhi * 4;
                    *(ushort4*)&ks[och * TN + (tok0 ^ ((och & 7) << 3))] = pk;
                }
            }
        }

        // ---- V projection (D[tok][och]), packed in registers
        ushort4 vpk[4][4];
        {
            f32x4 acc[4][4] = {};
            #pragma unroll
            for (int kk = 0; kk < 8; ++kk) {
                const int ch0 = kk * 32 + lhi * 8;
                bf16x8 af[4], bfr[4];
                #pragma unroll
                for (int tf = 0; tf < 4; ++tf) {
                    const int tok = tf * 16 + l15;
                    af[tf] = *(const bf16x8*)&xs[tok * CFULL + (ch0 ^ SWZ(tok))];
                }
                #pragma unroll
                for (int of = 0; of < 4; ++of) {
                    const int och = wv * 64 + of * 16 + l15;
                    bfr[of] = *(const bf16x8*)&Wv[och * CFULL + ch0];
                }
                #pragma unroll
                for (int tf = 0; tf < 4; ++tf)
                    #pragma unroll
                    for (int of = 0; of < 4; ++of)
                        acc[tf][of] = __builtin_amdgcn_mfma_f32_16x16x32_bf16(af[tf], bfr[of], acc[tf][of], 0, 0, 0);
            }
            #pragma unroll
            for (int tf = 0; tf < 4; ++tf) {
                #pragma unroll
                for (int of = 0; of < 4; ++of) {
                    const int och = wv * 64 + of * 16 + l15;
                    const float bias = bvl[och];
                    vpk[tf][of].x = bf16bits(acc[tf][of][0] + bias);
                    vpk[tf][of].y = bf16bits(acc[tf][of][1] + bias);
                    vpk[tf][of].z = bf16bits(acc[tf][of][2] + bias);
                    vpk[tf][of].w = bf16bits(acc[tf][of][3] + bias);
                }
            }
        }
        __syncthreads();              // everyone done reading xs
        #pragma unroll
        for (int tf = 0; tf < 4; ++tf)
            #pragma unroll
            for (int of = 0; of < 4; ++of) {
                const int och = wv * 64 + of * 16 + l15;
                const int tok0 = tf * 16 + lhi * 4;
                *(ushort4*)&xs[och * TN + (tok0 ^ ((och & 7) << 3))] = vpk[tf][of];
            }
        __syncthreads();

        // ---- kv accumulation (wave-local rows of ks/vs)
        {
            const int l31 = lane & 31;
            const int tb = (lane >> 5) * 8;
            #pragma unroll
            for (int h = 0; h < 2; ++h) {
                const int row = (wv * 2 + h) * CH + l31;
                f32x16& kva = h ? kvacc1 : kvacc0;
                #pragma unroll
                for (int ts = 0; ts < 4; ++ts) {
                    const int sw = (ts * 16 + tb) ^ ((row & 7) << 3);
                    bf16x8 ak = *(const bf16x8*)&ks[row * TN + sw];
                    bf16x8 av = *(const bf16x8*)&xs[row * TN + sw];
                    kva = __builtin_amdgcn_mfma_f32_32x32x16_bf16(ak, av, kva, 0, 0, 0);
                }
            }
        }
    }

    // ---- epilogue: ksum + kv atomics
    #pragma unroll
    for (int of = 0; of < 4; ++of) {
        float v = ksum[of];
        v += __shfl_xor(v, 16);
        v += __shfl_xor(v, 32);
        if (lhi == 0) atomicAdd(&ksws[b * CFULL + wv * 64 + of * 16 + l15], v);
    }
    {
        const int l31 = lane & 31;
        #pragma unroll
        for (int h = 0; h < 2; ++h) {
            const int p = wv * 2 + h;
            const f32x16& kva = h ? kvacc1 : kvacc0;
            #pragma unroll
            for (int r = 0; r < 16; ++r) {
                const int m = (r & 3) + 8 * (r >> 2) + 4 * (lane >> 5);
                atomicAdd(&kvws[((b * HEADS + p) * CH + m) * CH + l31], kva[r]);
            }
        }
    }
}

// ---------------------------------------------------------------------------
// Kernel 2: q = softplus(Wq x + bq); out[c,n] = sum_m kv[m,c] q[m,n] / (q.(ksum+eps))
// One 64-token tile per block -> 2048 blocks, 4 blocks/CU.
// ---------------------------------------------------------------------------
__global__ __launch_bounds__(256, 4)
void k2_out(const float* __restrict__ x,
            const unsigned short* __restrict__ Wq,
            const float* __restrict__ bq,
            const float* __restrict__ kvws, const float* __restrict__ ksws,
            float* __restrict__ outp)
{
    __shared__ __align__(16) unsigned short xs[TN * CFULL]; // staged x; later qs[tok][och]
    __shared__ float kse[CFULL];
    __shared__ float bql[CFULL];
    __shared__ float normls[HEADS][TN];

    const int tid = threadIdx.x;
    const int lane = tid & 63;
    const int wv = tid >> 6;
    const int l15 = lane & 15;
    const int lhi = lane >> 4;
    const int b = blockIdx.x >> 8;
    const int blk = blockIdx.x & 255;
    const int n0 = blk * TN;
    const float* xb = x + (size_t)b * CFULL * NTOK;
    float* ob = outp + (size_t)b * CFULL * NTOK;

    bql[tid] = bq[tid];
    kse[tid] = ksws[b * CFULL + tid] + EPS;

    stage_x(xb, n0, xs, wv, lane);
    __syncthreads();

    // ---- Q projection (D[och][tok])
    ushort4 qpk[4][4];
    {
        f32x4 acc[4][4] = {};
        #pragma unroll
        for (int kk = 0; kk < 8; ++kk) {
            const int ch0 = kk * 32 + lhi * 8;
            bf16x8 aw[4], bx[4];
            #pragma unroll
            for (int mf = 0; mf < 4; ++mf)
                aw[mf] = *(const bf16x8*)&Wq[(wv * 64 + mf * 16 + l15) * CFULL + ch0];
            #pragma unroll
            for (int nf = 0; nf < 4; ++nf) {
                const int tok = nf * 16 + l15;
                bx[nf] = *(const bf16x8*)&xs[tok * CFULL + (ch0 ^ SWZ(tok))];
            }
            #pragma unroll
            for (int mf = 0; mf < 4; ++mf)
                #pragma unroll
                for (int nf = 0; nf < 4; ++nf)
                    acc[mf][nf] = __builtin_amdgcn_mfma_f32_16x16x32_bf16(aw[mf], bx[nf], acc[mf][nf], 0, 0, 0);
        }
        #pragma unroll
        for (int mf = 0; mf < 4; ++mf) {
            #pragma unroll
            for (int nf = 0; nf < 4; ++nf) {
                const int och0 = wv * 64 + mf * 16 + lhi * 4;
                qpk[mf][nf].x = bf16bits(softplus_f(acc[mf][nf][0] + bql[och0 + 0]));
                qpk[mf][nf].y = bf16bits(softplus_f(acc[mf][nf][1] + bql[och0 + 1]));
                qpk[mf][nf].z = bf16bits(softplus_f(acc[mf][nf][2] + bql[och0 + 2]));
                qpk[mf][nf].w = bf16bits(softplus_f(acc[mf][nf][3] + bql[och0 + 3]));
            }
        }
    }
    __syncthreads();              // everyone done reading xs
    #pragma unroll
    for (int mf = 0; mf < 4; ++mf)
        #pragma unroll
        for (int nf = 0; nf < 4; ++nf) {
            const int tok = nf * 16 + l15;
            const int och0 = wv * 64 + mf * 16 + lhi * 4;
            *(ushort4*)&xs[tok * CFULL + (och0 ^ SWZ(tok))] = qpk[mf][nf];
        }
    __syncthreads();

    // ---- denominators (wave-local: heads 2wv, 2wv+1)
    #pragma unroll
    for (int h = 0; h < 2; ++h) {
        const int p = wv * 2 + h;
        float d = 0.f;
        #pragma unroll
        for (int mg = 0; mg < 4; ++mg) {
            bf16x8 qv = *(const bf16x8*)&xs[lane * CFULL + ((p * 32 + mg * 8) ^ SWZ(lane))];
            #pragma unroll
            for (int j = 0; j < 8; ++j)
                d += (float)qv[j] * kse[p * 32 + mg * 8 + j];
        }
        normls[p][lane] = 1.0f / d;
    }

    // ---- kv B-fragments in registers (loaded after Q-proj to cap VGPR pressure)
    bf16x8 bh[2][2];
    #pragma unroll
    for (int h = 0; h < 2; ++h) {
        const int base = (b * HEADS + wv * 2 + h) * CH * CH;
        #pragma unroll
        for (int hf = 0; hf < 2; ++hf) {
            #pragma unroll
            for (int j = 0; j < 8; ++j)
                bh[h][hf][j] = (__bf16)kvws[base + (lhi * 8 + j) * CH + hf * 16 + l15];
        }
    }
    __syncthreads();

    // ---- PV: D[tok][c] = sum_m q[m][tok] kv[m][c]; scale by norm; float4 stores
    #pragma unroll
    for (int h = 0; h < 2; ++h) {
        const int p = wv * 2 + h;
        #pragma unroll
        for (int nf = 0; nf < 4; ++nf) {
            const int tok = nf * 16 + l15;
            bf16x8 af = *(const bf16x8*)&xs[tok * CFULL + ((p * 32 + lhi * 8) ^ SWZ(tok))];
            f32x4 oA = {}, oB = {};
            oA = __builtin_amdgcn_mfma_f32_16x16x32_bf16(af, bh[h][0], oA, 0, 0, 0);
            oB = __builtin_amdgcn_mfma_f32_16x16x32_bf16(af, bh[h][1], oB, 0, 0, 0);
            const int tb = nf * 16 + lhi * 4;
            float4 sA, sB;
            sA.x = oA[0] * normls[p][tb + 0]; sA.y = oA[1] * normls[p][tb + 1];
            sA.z = oA[2] * normls[p][tb + 2]; sA.w = oA[3] * normls[p][tb + 3];
            sB.x = oB[0] * normls[p][tb + 0]; sB.y = oB[1] * normls[p][tb + 1];
            sB.z = oB[2] * normls[p][tb + 2]; sB.w = oB[3] * normls[p][tb + 3];
            *(float4*)&ob[(size_t)(p * 32 + l15) * NTOK + n0 + tb] = sA;
            *(float4*)&ob[(size_t)(p * 32 + 16 + l15) * NTOK + n0 + tb] = sB;
        }
    }
}

extern "C" void kernel_launch(void* const* d_in, const int* in_sizes, int n_in,
                              void* d_out, int out_size, void* d_ws, size_t ws_size,
                              hipStream_t stream)
{
    const float* x  = (const float*)d_in[0];
    const float* Wq = (const float*)d_in[1];
    const float* bq = (const float*)d_in[2];
    const float* Wk = (const float*)d_in[3];
    const float* bk = (const float*)d_in[4];
    const float* Wv = (const float*)d_in[5];
    const float* bv = (const float*)d_in[6];
    float* out = (float*)d_out;

    unsigned short* wbf = (unsigned short*)d_ws;                        // 3 * 65536 bf16
    float* kvws = (float*)((char*)d_ws + (size_t)3 * 65536 * 2);        // [8][8][32][32]
    float* ksws = kvws + BATCH * HEADS * CH * CH;                       // [8][256]

    hipMemsetAsync(kvws, 0, (BATCH * HEADS * CH * CH + BATCH * CFULL) * sizeof(float), stream);
    hipLaunchKernelGGL(prep_w, dim3(768), dim3(256), 0, stream, Wq, Wk, Wv, wbf);
    hipLaunchKernelGGL(k1_kv, dim3(BATCH * K1_BPB), dim3(256), 0, stream,
                       x, wbf + 65536, wbf + 2 * 65536, bk, bv, kvws, ksws);
    hipLaunchKernelGGL(k2_out, dim3(BATCH * 256), dim3(256), 0, stream,
                       x, wbf, bq, kvws, ksws, out);
}

// Round 3
// 332.909 us; speedup vs baseline: 2.1101x; 1.7133x over previous
//
#include <hip/hip_runtime.h>
#include <hip/hip_bf16.h>
#include <math.h>

#define BATCH 8
#define CFULL 256
#define HEADS 8
#define CH 32
#define NTOK 16384
#define TN 64
#define EPS 1e-6f

// xs tile swizzle: channel-index XOR spreads banks (units of 8 shorts = 16B)
#define SWZ(tok) ((((tok) & 7) << 3) ^ ((((tok) >> 3) & 3) << 6))

typedef __bf16 bf16x8 __attribute__((ext_vector_type(8)));
typedef float f32x4 __attribute__((ext_vector_type(4)));
typedef float f32x16 __attribute__((ext_vector_type(16)));

__device__ __forceinline__ unsigned short bf16bits(float f) {
    return __builtin_bit_cast(unsigned short, (__bf16)f);
}
__device__ __forceinline__ float softplus_f(float x) {
    return fmaxf(x, 0.0f) + __logf(1.0f + __expf(-fabsf(x)));
}

// 4x4 transpose within a quad of lanes.
__device__ __forceinline__ void quad_transpose(float4& a, int lane) {
    const bool o1 = lane & 1, o2 = lane & 2;
    float s1 = o1 ? a.x : a.y; float g1 = __shfl_xor(s1, 1);
    float s2 = o1 ? a.z : a.w; float g2 = __shfl_xor(s2, 1);
    a.x = o1 ? g1 : a.x;  a.y = o1 ? a.y : g1;
    a.z = o1 ? g2 : a.z;  a.w = o1 ? a.w : g2;
    float s3 = o2 ? a.x : a.z; float g3 = __shfl_xor(s3, 2);
    float s4 = o2 ? a.y : a.w; float g4 = __shfl_xor(s4, 2);
    a.x = o2 ? g3 : a.x;  a.z = o2 ? a.z : g3;
    a.y = o2 ? g4 : a.y;  a.w = o2 ? a.w : g4;
}

// ---- staging split for software pipelining -------------------------------
__device__ __forceinline__ void stage_load(const float* __restrict__ xb, int n0,
                                           int wv, int lane, float4* a) {
    const int q4 = lane & 3;
    const int t0 = (lane >> 2) << 2;
    #pragma unroll
    for (int g = 0; g < 16; ++g)
        a[g] = *(const float4*)(xb + (size_t)(wv * 64 + g * 4 + q4) * NTOK + n0 + t0);
}
__device__ __forceinline__ void stage_commit(float4* a, unsigned short* xs,
                                             int wv, int lane) {
    #pragma unroll
    for (int g = 0; g < 16; ++g) {
        float4 v = a[g];
        quad_transpose(v, lane);
        ushort4 pk;
        pk.x = bf16bits(v.x); pk.y = bf16bits(v.y);
        pk.z = bf16bits(v.z); pk.w = bf16bits(v.w);
        *(ushort4*)&xs[lane * CFULL + ((wv * 64 + g * 4) ^ SWZ(lane))] = pk;
    }
}

// Convert the three weight matrices to bf16 once per launch.
__global__ void prep_w(const float* __restrict__ Wq, const float* __restrict__ Wk,
                       const float* __restrict__ Wv, unsigned short* __restrict__ dst)
{
    const int i = blockIdx.x * 256 + threadIdx.x;
    const float* src = (i < 65536) ? Wq : ((i < 131072) ? Wk : Wv);
    dst[i] = bf16bits(src[i & 65535]);
}

// ---------------------------------------------------------------------------
// Kernel 1: k = softplus(Wk x + bk), v = Wv x + bv;
// per-block partials: kvp[bid][p][c][m] (f32), ksp[bid][ch] (f32). NO atomics.
// ---------------------------------------------------------------------------
__global__ __launch_bounds__(256, 2)
void k1_kv(const float* __restrict__ x,
           const unsigned short* __restrict__ Wk,
           const unsigned short* __restrict__ Wv,
           const float* __restrict__ bk, const float* __restrict__ bv,
           float* __restrict__ kvpart, float* __restrict__ kspart,
           int bpb, int ntiles)
{
    __shared__ __align__(16) unsigned short xs[TN * CFULL]; // staged x; later vs[och][tok]
    __shared__ __align__(16) unsigned short ks[CFULL * TN]; // k, och-major

    const int tid = threadIdx.x;
    const int lane = tid & 63;
    const int wv = tid >> 6;
    const int l15 = lane & 15;
    const int lhi = lane >> 4;
    const int bid = blockIdx.x;
    const int b = bid / bpb;
    const int blk = bid % bpb;
    const float* xb = x + (size_t)b * CFULL * NTOK;

    float bkr[4], bvr[4];
    #pragma unroll
    for (int of = 0; of < 4; ++of) {
        bkr[of] = bk[wv * 64 + of * 16 + l15];
        bvr[of] = bv[wv * 64 + of * 16 + l15];
    }

    f32x16 kvacc0 = {};
    f32x16 kvacc1 = {};
    float ksum[4] = {0.f, 0.f, 0.f, 0.f};
    float4 pf[16];

    stage_load(xb, blk * ntiles * TN, wv, lane, pf);

    for (int t = 0; t < ntiles; ++t) {
        __syncthreads();              // prev tile fully consumed
        stage_commit(pf, xs, wv, lane);
        if (t + 1 < ntiles)
            stage_load(xb, (blk * ntiles + t + 1) * TN, wv, lane, pf);
        __syncthreads();

        // ---- K projection (D[tok][och]) + softplus -> ks
        {
            f32x4 acc[4][4] = {};
            #pragma unroll
            for (int kk = 0; kk < 8; ++kk) {
                const int ch0 = kk * 32 + lhi * 8;
                bf16x8 af[4], bfr[4];
                #pragma unroll
                for (int tf = 0; tf < 4; ++tf) {
                    const int tok = tf * 16 + l15;
                    af[tf] = *(const bf16x8*)&xs[tok * CFULL + (ch0 ^ SWZ(tok))];
                }
                #pragma unroll
                for (int of = 0; of < 4; ++of) {
                    const int och = wv * 64 + of * 16 + l15;
                    bfr[of] = *(const bf16x8*)&Wk[och * CFULL + ch0];
                }
                #pragma unroll
                for (int tf = 0; tf < 4; ++tf)
                    #pragma unroll
                    for (int of = 0; of < 4; ++of)
                        acc[tf][of] = __builtin_amdgcn_mfma_f32_16x16x32_bf16(af[tf], bfr[of], acc[tf][of], 0, 0, 0);
            }
            #pragma unroll
            for (int tf = 0; tf < 4; ++tf) {
                #pragma unroll
                for (int of = 0; of < 4; ++of) {
                    const int och = wv * 64 + of * 16 + l15;
                    const float bias = bkr[of];
                    float v0 = softplus_f(acc[tf][of][0] + bias);
                    float v1 = softplus_f(acc[tf][of][1] + bias);
                    float v2 = softplus_f(acc[tf][of][2] + bias);
                    float v3 = softplus_f(acc[tf][of][3] + bias);
                    ksum[of] += v0 + v1 + v2 + v3;
                    ushort4 pk;
                    pk.x = bf16bits(v0); pk.y = bf16bits(v1);
                    pk.z = bf16bits(v2); pk.w = bf16bits(v3);
                    const int tok0 = tf * 16 + lhi * 4;
                    *(ushort4*)&ks[och * TN + (tok0 ^ ((och & 7) << 3))] = pk;
                }
            }
        }

        // ---- V projection (D[tok][och]), packed in registers
        ushort4 vpk[4][4];
        {
            f32x4 acc[4][4] = {};
            #pragma unroll
            for (int kk = 0; kk < 8; ++kk) {
                const int ch0 = kk * 32 + lhi * 8;
                bf16x8 af[4], bfr[4];
                #pragma unroll
                for (int tf = 0; tf < 4; ++tf) {
                    const int tok = tf * 16 + l15;
                    af[tf] = *(const bf16x8*)&xs[tok * CFULL + (ch0 ^ SWZ(tok))];
                }
                #pragma unroll
                for (int of = 0; of < 4; ++of) {
                    const int och = wv * 64 + of * 16 + l15;
                    bfr[of] = *(const bf16x8*)&Wv[och * CFULL + ch0];
                }
                #pragma unroll
                for (int tf = 0; tf < 4; ++tf)
                    #pragma unroll
                    for (int of = 0; of < 4; ++of)
                        acc[tf][of] = __builtin_amdgcn_mfma_f32_16x16x32_bf16(af[tf], bfr[of], acc[tf][of], 0, 0, 0);
            }
            #pragma unroll
            for (int tf = 0; tf < 4; ++tf) {
                #pragma unroll
                for (int of = 0; of < 4; ++of) {
                    const float bias = bvr[of];
                    vpk[tf][of].x = bf16bits(acc[tf][of][0] + bias);
                    vpk[tf][of].y = bf16bits(acc[tf][of][1] + bias);
                    vpk[tf][of].z = bf16bits(acc[tf][of][2] + bias);
                    vpk[tf][of].w = bf16bits(acc[tf][of][3] + bias);
                }
            }
        }
        __syncthreads();              // everyone done reading xs
        #pragma unroll
        for (int tf = 0; tf < 4; ++tf)
            #pragma unroll
            for (int of = 0; of < 4; ++of) {
                const int och = wv * 64 + of * 16 + l15;
                const int tok0 = tf * 16 + lhi * 4;
                *(ushort4*)&xs[och * TN + (tok0 ^ ((och & 7) << 3))] = vpk[tf][of];
            }
        __syncthreads();

        // ---- kv accumulation (wave-local rows of ks/vs)
        {
            const int l31 = lane & 31;
            const int tb = (lane >> 5) * 8;
            #pragma unroll
            for (int h = 0; h < 2; ++h) {
                const int row = (wv * 2 + h) * CH + l31;
                f32x16& kva = h ? kvacc1 : kvacc0;
                #pragma unroll
                for (int ts = 0; ts < 4; ++ts) {
                    const int sw = (ts * 16 + tb) ^ ((row & 7) << 3);
                    bf16x8 ak = *(const bf16x8*)&ks[row * TN + sw];
                    bf16x8 av = *(const bf16x8*)&xs[row * TN + sw];
                    kva = __builtin_amdgcn_mfma_f32_32x32x16_bf16(ak, av, kva, 0, 0, 0);
                }
            }
        }
    }

    // ---- epilogue: coalesced partial stores (no atomics)
    #pragma unroll
    for (int of = 0; of < 4; ++of) {
        float v = ksum[of];
        v += __shfl_xor(v, 16);
        v += __shfl_xor(v, 32);
        if (lhi == 0) kspart[bid * CFULL + wv * 64 + of * 16 + l15] = v;
    }
    {
        float* kvp = kvpart + ((size_t)bid << 13);
        const int l31 = lane & 31;
        const int hi = lane >> 5;
        #pragma unroll
        for (int h = 0; h < 2; ++h) {
            const int p = wv * 2 + h;
            const f32x16& kva = h ? kvacc1 : kvacc0;
            #pragma unroll
            for (int q = 0; q < 4; ++q) {
                // kva[4q..4q+3] are kv[m][c] with m = 8q+4hi+{0..3}, c = l31
                const int m0 = 8 * q + 4 * hi;
                float4 s;
                s.x = kva[4 * q + 0]; s.y = kva[4 * q + 1];
                s.z = kva[4 * q + 2]; s.w = kva[4 * q + 3];
                *(float4*)&kvp[p * 1024 + l31 * 32 + m0] = s;  // [p][c][m]
            }
        }
    }
}

// ---------------------------------------------------------------------------
// Reduce partials: kvT[b][p][c][m] (bf16), kse[b][ch] = ksum + EPS (f32)
// ---------------------------------------------------------------------------
__global__ __launch_bounds__(256)
void k1r(const float* __restrict__ kvpart, const float* __restrict__ kspart,
         unsigned short* __restrict__ kvT, float* __restrict__ kse, int bpb)
{
    const int o = blockIdx.x * 256 + threadIdx.x;   // 0..65535
    const int b = o >> 13;
    const int r = o & 8191;
    float s = 0.f;
    for (int j = 0; j < bpb; ++j)
        s += kvpart[((size_t)(b * bpb + j) << 13) + r];
    kvT[o] = bf16bits(s);
    if (blockIdx.x < BATCH) {
        const int bb = blockIdx.x;
        float t = 0.f;
        for (int j = 0; j < bpb; ++j)
            t += kspart[(bb * bpb + j) * CFULL + threadIdx.x];
        kse[bb * CFULL + threadIdx.x] = t + EPS;
    }
}

// ---------------------------------------------------------------------------
// Kernel 2: q = softplus(Wq x + bq); out[c,n] = sum_m kv[m,c] q[m,n] / (q.(kse))
// ---------------------------------------------------------------------------
__global__ __launch_bounds__(256, 4)
void k2_out(const float* __restrict__ x,
            const unsigned short* __restrict__ Wq,
            const float* __restrict__ bq,
            const unsigned short* __restrict__ kvT, const float* __restrict__ ksef,
            float* __restrict__ outp)
{
    __shared__ __align__(16) unsigned short xs[TN * CFULL]; // staged x; later qs[tok][och]
    __shared__ float kse[CFULL];
    __shared__ float bql[CFULL];
    __shared__ float normls[HEADS][TN];

    const int tid = threadIdx.x;
    const int lane = tid & 63;
    const int wv = tid >> 6;
    const int l15 = lane & 15;
    const int lhi = lane >> 4;
    const int b = blockIdx.x >> 8;
    const int blk = blockIdx.x & 255;
    const int n0 = blk * TN;
    const float* xb = x + (size_t)b * CFULL * NTOK;
    float* ob = outp + (size_t)b * CFULL * NTOK;

    bql[tid] = bq[tid];
    kse[tid] = ksef[b * CFULL + tid];

    {
        float4 pf[16];
        stage_load(xb, n0, wv, lane, pf);
        stage_commit(pf, xs, wv, lane);
    }
    __syncthreads();

    // ---- Q projection (D[och][tok])
    ushort4 qpk[4][4];
    {
        f32x4 acc[4][4] = {};
        #pragma unroll
        for (int kk = 0; kk < 8; ++kk) {
            const int ch0 = kk * 32 + lhi * 8;
            bf16x8 aw[4], bx[4];
            #pragma unroll
            for (int mf = 0; mf < 4; ++mf)
                aw[mf] = *(const bf16x8*)&Wq[(wv * 64 + mf * 16 + l15) * CFULL + ch0];
            #pragma unroll
            for (int nf = 0; nf < 4; ++nf) {
                const int tok = nf * 16 + l15;
                bx[nf] = *(const bf16x8*)&xs[tok * CFULL + (ch0 ^ SWZ(tok))];
            }
            #pragma unroll
            for (int mf = 0; mf < 4; ++mf)
                #pragma unroll
                for (int nf = 0; nf < 4; ++nf)
                    acc[mf][nf] = __builtin_amdgcn_mfma_f32_16x16x32_bf16(aw[mf], bx[nf], acc[mf][nf], 0, 0, 0);
        }
        #pragma unroll
        for (int mf = 0; mf < 4; ++mf) {
            #pragma unroll
            for (int nf = 0; nf < 4; ++nf) {
                const int och0 = wv * 64 + mf * 16 + lhi * 4;
                qpk[mf][nf].x = bf16bits(softplus_f(acc[mf][nf][0] + bql[och0 + 0]));
                qpk[mf][nf].y = bf16bits(softplus_f(acc[mf][nf][1] + bql[och0 + 1]));
                qpk[mf][nf].z = bf16bits(softplus_f(acc[mf][nf][2] + bql[och0 + 2]));
                qpk[mf][nf].w = bf16bits(softplus_f(acc[mf][nf][3] + bql[och0 + 3]));
            }
        }
    }
    __syncthreads();              // everyone done reading xs
    #pragma unroll
    for (int mf = 0; mf < 4; ++mf)
        #pragma unroll
        for (int nf = 0; nf < 4; ++nf) {
            const int tok = nf * 16 + l15;
            const int och0 = wv * 64 + mf * 16 + lhi * 4;
            *(ushort4*)&xs[tok * CFULL + (och0 ^ SWZ(tok))] = qpk[mf][nf];
        }
    __syncthreads();

    // ---- denominators (wave-local: heads 2wv, 2wv+1)
    #pragma unroll
    for (int h = 0; h < 2; ++h) {
        const int p = wv * 2 + h;
        float d = 0.f;
        #pragma unroll
        for (int mg = 0; mg < 4; ++mg) {
            bf16x8 qv = *(const bf16x8*)&xs[lane * CFULL + ((p * 32 + mg * 8) ^ SWZ(lane))];
            #pragma unroll
            for (int j = 0; j < 8; ++j)
                d += (float)qv[j] * kse[p * 32 + mg * 8 + j];
        }
        normls[p][lane] = 1.0f / d;
    }

    // ---- kv B-fragments (bf16, vectorized from kvT[b][p][c][m])
    bf16x8 bh[2][2];
    #pragma unroll
    for (int h = 0; h < 2; ++h) {
        const int base = (b * HEADS + wv * 2 + h) << 10;
        #pragma unroll
        for (int hf = 0; hf < 2; ++hf)
            bh[h][hf] = *(const bf16x8*)&kvT[base + (hf * 16 + l15) * 32 + lhi * 8];
    }
    __syncthreads();

    // ---- PV: D[tok][c] = sum_m q[m][tok] kv[m][c]; scale by norm; float4 stores
    #pragma unroll
    for (int h = 0; h < 2; ++h) {
        const int p = wv * 2 + h;
        #pragma unroll
        for (int nf = 0; nf < 4; ++nf) {
            const int tok = nf * 16 + l15;
            bf16x8 af = *(const bf16x8*)&xs[tok * CFULL + ((p * 32 + lhi * 8) ^ SWZ(tok))];
            f32x4 oA = {}, oB = {};
            oA = __builtin_amdgcn_mfma_f32_16x16x32_bf16(af, bh[h][0], oA, 0, 0, 0);
            oB = __builtin_amdgcn_mfma_f32_16x16x32_bf16(af, bh[h][1], oB, 0, 0, 0);
            const int tb = nf * 16 + lhi * 4;
            float4 sA, sB;
            sA.x = oA[0] * normls[p][tb + 0]; sA.y = oA[1] * normls[p][tb + 1];
            sA.z = oA[2] * normls[p][tb + 2]; sA.w = oA[3] * normls[p][tb + 3];
            sB.x = oB[0] * normls[p][tb + 0]; sB.y = oB[1] * normls[p][tb + 1];
            sB.z = oB[2] * normls[p][tb + 2]; sB.w = oB[3] * normls[p][tb + 3];
            *(float4*)&ob[(size_t)(p * 32 + l15) * NTOK + n0 + tb] = sA;
            *(float4*)&ob[(size_t)(p * 32 + 16 + l15) * NTOK + n0 + tb] = sB;
        }
    }
}

extern "C" void kernel_launch(void* const* d_in, const int* in_sizes, int n_in,
                              void* d_out, int out_size, void* d_ws, size_t ws_size,
                              hipStream_t stream)
{
    const float* x  = (const float*)d_in[0];
    const float* Wq = (const float*)d_in[1];
    const float* bq = (const float*)d_in[2];
    const float* Wk = (const float*)d_in[3];
    const float* bk = (const float*)d_in[4];
    const float* Wv = (const float*)d_in[5];
    const float* bv = (const float*)d_in[6];
    float* out = (float*)d_out;

    unsigned char* ws = (unsigned char*)d_ws;
    unsigned short* wbf = (unsigned short*)ws;                    // 384 KB
    unsigned short* kvT = (unsigned short*)(ws + 393216);         // 128 KB
    float* kse = (float*)(ws + 524288);                           // 8 KB
    float* kspart = (float*)(ws + 532480);                        // bpb*8*256*4

    // choose partial-slab count by available workspace
    int bpb = 64;
    size_t ksp_sz = (size_t)BATCH * 64 * CFULL * 4;
    size_t kvp_off = 532480 + ksp_sz;
    if (ws_size < kvp_off + ((size_t)BATCH * 64 * 8192 * 4)) {
        bpb = 16;
        ksp_sz = (size_t)BATCH * 16 * CFULL * 4;
        kvp_off = 532480 + ksp_sz;
    }
    float* kvpart = (float*)(ws + kvp_off);
    const int ntiles = NTOK / TN / bpb;

    hipLaunchKernelGGL(prep_w, dim3(768), dim3(256), 0, stream, Wq, Wk, Wv, wbf);
    hipLaunchKernelGGL(k1_kv, dim3(BATCH * bpb), dim3(256), 0, stream,
                       x, wbf + 65536, wbf + 2 * 65536, bk, bv, kvpart, kspart, bpb, ntiles);
    hipLaunchKernelGGL(k1r, dim3(256), dim3(256), 0, stream,
                       kvpart, kspart, kvT, kse, bpb);
    hipLaunchKernelGGL(k2_out, dim3(BATCH * 256), dim3(256), 0, stream,
                       x, wbf, bq, kvT, kse, out);
}

// Round 4
// 303.095 us; speedup vs baseline: 2.3177x; 1.0984x over previous
//
#include <hip/hip_runtime.h>
#include <hip/hip_bf16.h>
#include <math.h>

#define BATCH 8
#define CFULL 256
#define HEADS 8
#define CH 32
#define NTOK 16384
#define TN 64
#define EPS 1e-6f

// xs tile swizzle: channel-index XOR spreads banks (units of 8 shorts = 16B)
#define SWZ(tok) ((((tok) & 7) << 3) ^ ((((tok) >> 3) & 3) << 6))

typedef __bf16 bf16x8 __attribute__((ext_vector_type(8)));
typedef float f32x4 __attribute__((ext_vector_type(4)));
typedef float f32x16 __attribute__((ext_vector_type(16)));
typedef float fvec4 __attribute__((ext_vector_type(4)));

__device__ __forceinline__ unsigned short bf16bits(float f) {
    return __builtin_bit_cast(unsigned short, (__bf16)f);
}
__device__ __forceinline__ float softplus_f(float x) {
    return fmaxf(x, 0.0f) + __logf(1.0f + __expf(-fabsf(x)));
}

// 4x4 transpose within a quad of lanes.
__device__ __forceinline__ void quad_transpose(fvec4& a, int lane) {
    const bool o1 = lane & 1, o2 = lane & 2;
    float s1 = o1 ? a.x : a.y; float g1 = __shfl_xor(s1, 1);
    float s2 = o1 ? a.z : a.w; float g2 = __shfl_xor(s2, 1);
    a.x = o1 ? g1 : a.x;  a.y = o1 ? a.y : g1;
    a.z = o1 ? g2 : a.z;  a.w = o1 ? a.w : g2;
    float s3 = o2 ? a.x : a.z; float g3 = __shfl_xor(s3, 2);
    float s4 = o2 ? a.y : a.w; float g4 = __shfl_xor(s4, 2);
    a.x = o2 ? g3 : a.x;  a.z = o2 ? a.z : g3;
    a.y = o2 ? g4 : a.y;  a.w = o2 ? a.w : g4;
}

// Stage one 64-token x tile into xs (tok-major bf16, SWZ swizzled).
// Coalesced (4 rows x 256B per instruction) + non-temporal (x is read-once:
// keep the stream out of L2 so Wk/Wv/Wq stay resident).
__device__ __forceinline__ void stage_x(const float* __restrict__ xb, int n0,
                                        unsigned short* xs, int wv, int lane) {
    const int q4 = lane & 3;
    const int t0 = (lane >> 2) << 2;
    #pragma unroll
    for (int g = 0; g < 16; ++g) {
        const int c0 = wv * 64 + g * 4;
        fvec4 a = __builtin_nontemporal_load(
            (const fvec4*)(xb + (size_t)(c0 + q4) * NTOK + n0 + t0));
        quad_transpose(a, lane);
        ushort4 pk;
        pk.x = bf16bits(a.x); pk.y = bf16bits(a.y);
        pk.z = bf16bits(a.z); pk.w = bf16bits(a.w);
        *(ushort4*)&xs[lane * CFULL + (c0 ^ SWZ(lane))] = pk;
    }
}

// Convert the three weight matrices to bf16 once per launch.
__global__ void prep_w(const float* __restrict__ Wq, const float* __restrict__ Wk,
                       const float* __restrict__ Wv, unsigned short* __restrict__ dst)
{
    const int i = blockIdx.x * 256 + threadIdx.x;
    const float* src = (i < 65536) ? Wq : ((i < 131072) ? Wk : Wv);
    dst[i] = bf16bits(src[i & 65535]);
}

// ---------------------------------------------------------------------------
// Kernel 1: k = softplus(Wk x + bk), v = Wv x + bv;
// per-block partials: kvp[bid][p][c][m] (f32), ksp[bid][ch] (f32). NO atomics.
// ---------------------------------------------------------------------------
__global__ __launch_bounds__(256, 2)
void k1_kv(const float* __restrict__ x,
           const unsigned short* __restrict__ Wk,
           const unsigned short* __restrict__ Wv,
           const float* __restrict__ bk, const float* __restrict__ bv,
           float* __restrict__ kvpart, float* __restrict__ kspart,
           int bpb, int ntiles)
{
    __shared__ __align__(16) unsigned short xs[TN * CFULL]; // staged x; later vs[och][tok]
    __shared__ __align__(16) unsigned short ks[CFULL * TN]; // k, och-major

    const int tid = threadIdx.x;
    const int lane = tid & 63;
    const int wv = tid >> 6;
    const int l15 = lane & 15;
    const int lhi = lane >> 4;
    const int bid = blockIdx.x;
    const int b = bid / bpb;
    const int blk = bid % bpb;
    const float* xb = x + (size_t)b * CFULL * NTOK;

    float bkr[4], bvr[4];
    #pragma unroll
    for (int of = 0; of < 4; ++of) {
        bkr[of] = bk[wv * 64 + of * 16 + l15];
        bvr[of] = bv[wv * 64 + of * 16 + l15];
    }

    f32x16 kvacc0 = {};
    f32x16 kvacc1 = {};
    float ksum[4] = {0.f, 0.f, 0.f, 0.f};

    for (int t = 0; t < ntiles; ++t) {
        __syncthreads();              // prev tile fully consumed
        stage_x(xb, (blk * ntiles + t) * TN, xs, wv, lane);
        __syncthreads();

        // ---- K projection (D[tok][och]) + softplus -> ks
        {
            f32x4 acc[4][4] = {};
            #pragma unroll
            for (int kk = 0; kk < 8; ++kk) {
                const int ch0 = kk * 32 + lhi * 8;
                bf16x8 af[4], bfr[4];
                #pragma unroll
                for (int tf = 0; tf < 4; ++tf) {
                    const int tok = tf * 16 + l15;
                    af[tf] = *(const bf16x8*)&xs[tok * CFULL + (ch0 ^ SWZ(tok))];
                }
                #pragma unroll
                for (int of = 0; of < 4; ++of) {
                    const int och = wv * 64 + of * 16 + l15;
                    bfr[of] = *(const bf16x8*)&Wk[och * CFULL + ch0];
                }
                #pragma unroll
                for (int tf = 0; tf < 4; ++tf)
                    #pragma unroll
                    for (int of = 0; of < 4; ++of)
                        acc[tf][of] = __builtin_amdgcn_mfma_f32_16x16x32_bf16(af[tf], bfr[of], acc[tf][of], 0, 0, 0);
            }
            #pragma unroll
            for (int tf = 0; tf < 4; ++tf) {
                #pragma unroll
                for (int of = 0; of < 4; ++of) {
                    const int och = wv * 64 + of * 16 + l15;
                    const float bias = bkr[of];
                    float v0 = softplus_f(acc[tf][of][0] + bias);
                    float v1 = softplus_f(acc[tf][of][1] + bias);
                    float v2 = softplus_f(acc[tf][of][2] + bias);
                    float v3 = softplus_f(acc[tf][of][3] + bias);
                    ksum[of] += v0 + v1 + v2 + v3;
                    ushort4 pk;
                    pk.x = bf16bits(v0); pk.y = bf16bits(v1);
                    pk.z = bf16bits(v2); pk.w = bf16bits(v3);
                    const int tok0 = tf * 16 + lhi * 4;
                    *(ushort4*)&ks[och * TN + (tok0 ^ ((och & 7) << 3))] = pk;
                }
            }
        }

        // ---- V projection (D[tok][och]), packed in registers
        ushort4 vpk[4][4];
        {
            f32x4 acc[4][4] = {};
            #pragma unroll
            for (int kk = 0; kk < 8; ++kk) {
                const int ch0 = kk * 32 + lhi * 8;
                bf16x8 af[4], bfr[4];
                #pragma unroll
                for (int tf = 0; tf < 4; ++tf) {
                    const int tok = tf * 16 + l15;
                    af[tf] = *(const bf16x8*)&xs[tok * CFULL + (ch0 ^ SWZ(tok))];
                }
                #pragma unroll
                for (int of = 0; of < 4; ++of) {
                    const int och = wv * 64 + of * 16 + l15;
                    bfr[of] = *(const bf16x8*)&Wv[och * CFULL + ch0];
                }
                #pragma unroll
                for (int tf = 0; tf < 4; ++tf)
                    #pragma unroll
                    for (int of = 0; of < 4; ++of)
                        acc[tf][of] = __builtin_amdgcn_mfma_f32_16x16x32_bf16(af[tf], bfr[of], acc[tf][of], 0, 0, 0);
            }
            #pragma unroll
            for (int tf = 0; tf < 4; ++tf) {
                #pragma unroll
                for (int of = 0; of < 4; ++of) {
                    const float bias = bvr[of];
                    vpk[tf][of].x = bf16bits(acc[tf][of][0] + bias);
                    vpk[tf][of].y = bf16bits(acc[tf][of][1] + bias);
                    vpk[tf][of].z = bf16bits(acc[tf][of][2] + bias);
                    vpk[tf][of].w = bf16bits(acc[tf][of][3] + bias);
                }
            }
        }
        __syncthreads();              // everyone done reading xs
        #pragma unroll
        for (int tf = 0; tf < 4; ++tf)
            #pragma unroll
            for (int of = 0; of < 4; ++of) {
                const int och = wv * 64 + of * 16 + l15;
                const int tok0 = tf * 16 + lhi * 4;
                *(ushort4*)&xs[och * TN + (tok0 ^ ((och & 7) << 3))] = vpk[tf][of];
            }
        __syncthreads();

        // ---- kv accumulation (wave-local rows of ks/vs)
        {
            const int l31 = lane & 31;
            const int tb = (lane >> 5) * 8;
            #pragma unroll
            for (int h = 0; h < 2; ++h) {
                const int row = (wv * 2 + h) * CH + l31;
                f32x16& kva = h ? kvacc1 : kvacc0;
                #pragma unroll
                for (int ts = 0; ts < 4; ++ts) {
                    const int sw = (ts * 16 + tb) ^ ((row & 7) << 3);
                    bf16x8 ak = *(const bf16x8*)&ks[row * TN + sw];
                    bf16x8 av = *(const bf16x8*)&xs[row * TN + sw];
                    kva = __builtin_amdgcn_mfma_f32_32x32x16_bf16(ak, av, kva, 0, 0, 0);
                }
            }
        }
    }

    // ---- epilogue: coalesced partial stores (no atomics)
    #pragma unroll
    for (int of = 0; of < 4; ++of) {
        float v = ksum[of];
        v += __shfl_xor(v, 16);
        v += __shfl_xor(v, 32);
        if (lhi == 0) kspart[bid * CFULL + wv * 64 + of * 16 + l15] = v;
    }
    {
        float* kvp = kvpart + ((size_t)bid << 13);
        const int l31 = lane & 31;
        const int hi = lane >> 5;
        #pragma unroll
        for (int h = 0; h < 2; ++h) {
            const int p = wv * 2 + h;
            const f32x16& kva = h ? kvacc1 : kvacc0;
            #pragma unroll
            for (int q = 0; q < 4; ++q) {
                const int m0 = 8 * q + 4 * hi;
                f32x4 s;
                s[0] = kva[4 * q + 0]; s[1] = kva[4 * q + 1];
                s[2] = kva[4 * q + 2]; s[3] = kva[4 * q + 3];
                *(f32x4*)&kvp[p * 1024 + l31 * 32 + m0] = s;  // [p][c][m]
            }
        }
    }
}

// ---------------------------------------------------------------------------
// Reduce partials: kvT[b][p][c][m] (bf16), kse[b][ch] = ksum + EPS (f32)
// ---------------------------------------------------------------------------
__global__ __launch_bounds__(256)
void k1r(const float* __restrict__ kvpart, const float* __restrict__ kspart,
         unsigned short* __restrict__ kvT, float* __restrict__ kse, int bpb)
{
    const int o = blockIdx.x * 256 + threadIdx.x;   // 0..65535
    const int b = o >> 13;
    const int r = o & 8191;
    float s = 0.f;
    for (int j = 0; j < bpb; ++j)
        s += kvpart[((size_t)(b * bpb + j) << 13) + r];
    kvT[o] = bf16bits(s);
    if (blockIdx.x < BATCH) {
        const int bb = blockIdx.x;
        float t = 0.f;
        for (int j = 0; j < bpb; ++j)
            t += kspart[(bb * bpb + j) * CFULL + threadIdx.x];
        kse[bb * CFULL + threadIdx.x] = t + EPS;
    }
}

// ---------------------------------------------------------------------------
// Kernel 2: q = softplus(Wq x + bq); out[c,n] = sum_m kv[m,c] q[m,n] / (q.(kse))
// ---------------------------------------------------------------------------
__global__ __launch_bounds__(256, 4)
void k2_out(const float* __restrict__ x,
            const unsigned short* __restrict__ Wq,
            const float* __restrict__ bq,
            const unsigned short* __restrict__ kvT, const float* __restrict__ ksef,
            float* __restrict__ outp)
{
    __shared__ __align__(16) unsigned short xs[TN * CFULL]; // staged x; later qs[tok][och]
    __shared__ float kse[CFULL];
    __shared__ float bql[CFULL];
    __shared__ float normls[HEADS][TN];

    const int tid = threadIdx.x;
    const int lane = tid & 63;
    const int wv = tid >> 6;
    const int l15 = lane & 15;
    const int lhi = lane >> 4;
    const int b = blockIdx.x >> 8;
    const int blk = blockIdx.x & 255;
    const int n0 = blk * TN;
    const float* xb = x + (size_t)b * CFULL * NTOK;
    float* ob = outp + (size_t)b * CFULL * NTOK;

    bql[tid] = bq[tid];
    kse[tid] = ksef[b * CFULL + tid];

    stage_x(xb, n0, xs, wv, lane);
    __syncthreads();

    // ---- Q projection (D[och][tok])
    ushort4 qpk[4][4];
    {
        f32x4 acc[4][4] = {};
        #pragma unroll
        for (int kk = 0; kk < 8; ++kk) {
            const int ch0 = kk * 32 + lhi * 8;
            bf16x8 aw[4], bx[4];
            #pragma unroll
            for (int mf = 0; mf < 4; ++mf)
                aw[mf] = *(const bf16x8*)&Wq[(wv * 64 + mf * 16 + l15) * CFULL + ch0];
            #pragma unroll
            for (int nf = 0; nf < 4; ++nf) {
                const int tok = nf * 16 + l15;
                bx[nf] = *(const bf16x8*)&xs[tok * CFULL + (ch0 ^ SWZ(tok))];
            }
            #pragma unroll
            for (int mf = 0; mf < 4; ++mf)
                #pragma unroll
                for (int nf = 0; nf < 4; ++nf)
                    acc[mf][nf] = __builtin_amdgcn_mfma_f32_16x16x32_bf16(aw[mf], bx[nf], acc[mf][nf], 0, 0, 0);
        }
        #pragma unroll
        for (int mf = 0; mf < 4; ++mf) {
            #pragma unroll
            for (int nf = 0; nf < 4; ++nf) {
                const int och0 = wv * 64 + mf * 16 + lhi * 4;
                qpk[mf][nf].x = bf16bits(softplus_f(acc[mf][nf][0] + bql[och0 + 0]));
                qpk[mf][nf].y = bf16bits(softplus_f(acc[mf][nf][1] + bql[och0 + 1]));
                qpk[mf][nf].z = bf16bits(softplus_f(acc[mf][nf][2] + bql[och0 + 2]));
                qpk[mf][nf].w = bf16bits(softplus_f(acc[mf][nf][3] + bql[och0 + 3]));
            }
        }
    }
    __syncthreads();              // everyone done reading xs
    #pragma unroll
    for (int mf = 0; mf < 4; ++mf)
        #pragma unroll
        for (int nf = 0; nf < 4; ++nf) {
            const int tok = nf * 16 + l15;
            const int och0 = wv * 64 + mf * 16 + lhi * 4;
            *(ushort4*)&xs[tok * CFULL + (och0 ^ SWZ(tok))] = qpk[mf][nf];
        }
    __syncthreads();

    // ---- denominators (wave-local: heads 2wv, 2wv+1)
    #pragma unroll
    for (int h = 0; h < 2; ++h) {
        const int p = wv * 2 + h;
        float d = 0.f;
        #pragma unroll
        for (int mg = 0; mg < 4; ++mg) {
            bf16x8 qv = *(const bf16x8*)&xs[lane * CFULL + ((p * 32 + mg * 8) ^ SWZ(lane))];
            #pragma unroll
            for (int j = 0; j < 8; ++j)
                d += (float)qv[j] * kse[p * 32 + mg * 8 + j];
        }
        normls[p][lane] = 1.0f / d;
    }

    // ---- kv B-fragments (bf16, vectorized from kvT[b][p][c][m])
    bf16x8 bh[2][2];
    #pragma unroll
    for (int h = 0; h < 2; ++h) {
        const int base = (b * HEADS + wv * 2 + h) << 10;
        #pragma unroll
        for (int hf = 0; hf < 2; ++hf)
            bh[h][hf] = *(const bf16x8*)&kvT[base + (hf * 16 + l15) * 32 + lhi * 8];
    }
    __syncthreads();

    // ---- PV: D[tok][c] = sum_m q[m][tok] kv[m][c]; scale by norm; nt float4 stores
    #pragma unroll
    for (int h = 0; h < 2; ++h) {
        const int p = wv * 2 + h;
        #pragma unroll
        for (int nf = 0; nf < 4; ++nf) {
            const int tok = nf * 16 + l15;
            bf16x8 af = *(const bf16x8*)&xs[tok * CFULL + ((p * 32 + lhi * 8) ^ SWZ(tok))];
            f32x4 oA = {}, oB = {};
            oA = __builtin_amdgcn_mfma_f32_16x16x32_bf16(af, bh[h][0], oA, 0, 0, 0);
            oB = __builtin_amdgcn_mfma_f32_16x16x32_bf16(af, bh[h][1], oB, 0, 0, 0);
            const int tb = nf * 16 + lhi * 4;
            f32x4 sA, sB;
            sA[0] = oA[0] * normls[p][tb + 0]; sA[1] = oA[1] * normls[p][tb + 1];
            sA[2] = oA[2] * normls[p][tb + 2]; sA[3] = oA[3] * normls[p][tb + 3];
            sB[0] = oB[0] * normls[p][tb + 0]; sB[1] = oB[1] * normls[p][tb + 1];
            sB[2] = oB[2] * normls[p][tb + 2]; sB[3] = oB[3] * normls[p][tb + 3];
            __builtin_nontemporal_store(sA, (f32x4*)&ob[(size_t)(p * 32 + l15) * NTOK + n0 + tb]);
            __builtin_nontemporal_store(sB, (f32x4*)&ob[(size_t)(p * 32 + 16 + l15) * NTOK + n0 + tb]);
        }
    }
}

extern "C" void kernel_launch(void* const* d_in, const int* in_sizes, int n_in,
                              void* d_out, int out_size, void* d_ws, size_t ws_size,
                              hipStream_t stream)
{
    const float* x  = (const float*)d_in[0];
    const float* Wq = (const float*)d_in[1];
    const float* bq = (const float*)d_in[2];
    const float* Wk = (const float*)d_in[3];
    const float* bk = (const float*)d_in[4];
    const float* Wv = (const float*)d_in[5];
    const float* bv = (const float*)d_in[6];
    float* out = (float*)d_out;

    unsigned char* ws = (unsigned char*)d_ws;
    unsigned short* wbf = (unsigned short*)ws;                    // 384 KB
    unsigned short* kvT = (unsigned short*)(ws + 393216);         // 128 KB
    float* kse = (float*)(ws + 524288);                           // 8 KB
    float* kspart = (float*)(ws + 532480);                        // bpb*8*256*4

    int bpb = 64;
    size_t ksp_sz = (size_t)BATCH * 64 * CFULL * 4;
    size_t kvp_off = 532480 + ksp_sz;
    if (ws_size < kvp_off + ((size_t)BATCH * 64 * 8192 * 4)) {
        bpb = 16;
        ksp_sz = (size_t)BATCH * 16 * CFULL * 4;
        kvp_off = 532480 + ksp_sz;
    }
    float* kvpart = (float*)(ws + kvp_off);
    const int ntiles = NTOK / TN / bpb;

    hipLaunchKernelGGL(prep_w, dim3(768), dim3(256), 0, stream, Wq, Wk, Wv, wbf);
    hipLaunchKernelGGL(k1_kv, dim3(BATCH * bpb), dim3(256), 0, stream,
                       x, wbf + 65536, wbf + 2 * 65536, bk, bv, kvpart, kspart, bpb, ntiles);
    hipLaunchKernelGGL(k1r, dim3(256), dim3(256), 0, stream,
                       kvpart, kspart, kvT, kse, bpb);
    hipLaunchKernelGGL(k2_out, dim3(BATCH * 256), dim3(256), 0, stream,
                       x, wbf, bq, kvT, kse, out);
}

// Round 5
// 273.540 us; speedup vs baseline: 2.5681x; 1.1080x over previous
//
#include <hip/hip_runtime.h>
#include <hip/hip_bf16.h>
#include <math.h>

#define BATCH 8
#define CFULL 256
#define HEADS 8
#define CH 32
#define NTOK 16384
#define TN 64
#define EPS 1e-6f

// xs tile swizzle: channel-index XOR spreads banks (units of 8 shorts = 16B)
#define SWZ(tok) ((((tok) & 7) << 3) ^ ((((tok) >> 3) & 3) << 6))

typedef __bf16 bf16x8 __attribute__((ext_vector_type(8)));
typedef float f32x4 __attribute__((ext_vector_type(4)));
typedef float f32x16 __attribute__((ext_vector_type(16)));
typedef float fvec4 __attribute__((ext_vector_type(4)));
typedef unsigned short ushort8v __attribute__((ext_vector_type(8)));
typedef int int4v __attribute__((ext_vector_type(4)));

__device__ __forceinline__ unsigned short bf16bits(float f) {
    return __builtin_bit_cast(unsigned short, (__bf16)f);
}
__device__ __forceinline__ float softplus_f(float x) {
    return fmaxf(x, 0.0f) + __logf(1.0f + __expf(-fabsf(x)));
}

// 4x4 transpose within a quad of lanes.
__device__ __forceinline__ void quad_transpose(fvec4& a, int lane) {
    const bool o1 = lane & 1, o2 = lane & 2;
    float s1 = o1 ? a.x : a.y; float g1 = __shfl_xor(s1, 1);
    float s2 = o1 ? a.z : a.w; float g2 = __shfl_xor(s2, 1);
    a.x = o1 ? g1 : a.x;  a.y = o1 ? a.y : g1;
    a.z = o1 ? g2 : a.z;  a.w = o1 ? a.w : g2;
    float s3 = o2 ? a.x : a.z; float g3 = __shfl_xor(s3, 2);
    float s4 = o2 ? a.y : a.w; float g4 = __shfl_xor(s4, 2);
    a.x = o2 ? g3 : a.x;  a.z = o2 ? a.z : g3;
    a.y = o2 ? g4 : a.y;  a.w = o2 ? a.w : g4;
}

// Stage one 64-token x tile into xs (tok-major bf16, SWZ swizzled) from f32 x.
__device__ __forceinline__ void stage_x(const float* __restrict__ xb, int n0,
                                        unsigned short* xs, int wv, int lane) {
    const int q4 = lane & 3;
    const int t0 = (lane >> 2) << 2;
    #pragma unroll
    for (int g = 0; g < 16; ++g) {
        const int c0 = wv * 64 + g * 4;
        fvec4 a = __builtin_nontemporal_load(
            (const fvec4*)(xb + (size_t)(c0 + q4) * NTOK + n0 + t0));
        quad_transpose(a, lane);
        ushort4 pk;
        pk.x = bf16bits(a.x); pk.y = bf16bits(a.y);
        pk.z = bf16bits(a.z); pk.w = bf16bits(a.w);
        *(ushort4*)&xs[lane * CFULL + (c0 ^ SWZ(lane))] = pk;
    }
}

// Stage one 64-token tile from pre-transposed/pre-swizzled xT (bf16): pure copy.
// Wave wv copies tok rows [wv*16, wv*16+16) = 8 KB, 8 x ushort8 per lane.
__device__ __forceinline__ void stage_tile(const unsigned short* __restrict__ xTb,
                                           int n0, unsigned short* xs, int wv, int lane) {
    const unsigned short* src = xTb + (size_t)(n0 + wv * 16) * CFULL;
    unsigned short* dst = &xs[wv * 16 * CFULL];
    const int off = lane * 8;
    #pragma unroll
    for (int i = 0; i < 8; ++i) {
        ushort8v v = __builtin_nontemporal_load((const ushort8v*)&src[i * 512 + off]);
        *(ushort8v*)&dst[i * 512 + off] = v;
    }
}

// Convert the three weight matrices to bf16 once per launch.
__global__ void prep_w(const float* __restrict__ Wq, const float* __restrict__ Wk,
                       const float* __restrict__ Wv, unsigned short* __restrict__ dst)
{
    const int i = blockIdx.x * 256 + threadIdx.x;
    const float* src = (i < 65536) ? Wq : ((i < 131072) ? Wk : Wv);
    dst[i] = bf16bits(src[i & 65535]);
}

// ---------------------------------------------------------------------------
// Transpose kernel: x[b][ch][tok] f32 -> xT[b][tok][ch] bf16, pre-swizzled.
// ---------------------------------------------------------------------------
__global__ __launch_bounds__(256, 4)
void xpose(const float* __restrict__ x, unsigned short* __restrict__ xT)
{
    __shared__ __align__(16) unsigned short xs[TN * CFULL];
    const int tid = threadIdx.x;
    const int lane = tid & 63;
    const int wv = tid >> 6;
    const int b = blockIdx.x >> 8;
    const int n0 = (blockIdx.x & 255) * TN;

    stage_x(x + (size_t)b * CFULL * NTOK, n0, xs, wv, lane);
    __syncthreads();
    // dump 32 KB linearly, coalesced + nt
    int4v* dst = (int4v*)(xT + (size_t)b * NTOK * CFULL + (size_t)n0 * CFULL);
    const int4v* src = (const int4v*)xs;
    #pragma unroll
    for (int i = 0; i < 8; ++i)
        __builtin_nontemporal_store(src[i * 256 + tid], &dst[i * 256 + tid]);
}

// ---------------------------------------------------------------------------
// Kernel 1: k = softplus(Wk x + bk), v = Wv x + bv;
// per-block partials: kvp[bid][p][c][m] (f32), ksp[bid][ch] (f32). NO atomics.
// ---------------------------------------------------------------------------
__global__ __launch_bounds__(256)
void k1_kv(const float* __restrict__ x, const unsigned short* __restrict__ xT,
           const unsigned short* __restrict__ Wk,
           const unsigned short* __restrict__ Wv,
           const float* __restrict__ bk, const float* __restrict__ bv,
           float* __restrict__ kvpart, float* __restrict__ kspart,
           int bpb, int ntiles, int use_xT)
{
    __shared__ __align__(16) unsigned short xs[TN * CFULL]; // staged x; later vs[och][tok]
    __shared__ __align__(16) unsigned short ks[CFULL * TN]; // k, och-major

    const int tid = threadIdx.x;
    const int lane = tid & 63;
    const int wv = tid >> 6;
    const int l15 = lane & 15;
    const int lhi = lane >> 4;
    const int bid = blockIdx.x;
    const int b = bid / bpb;
    const int blk = bid % bpb;
    const float* xb = x + (size_t)b * CFULL * NTOK;
    const unsigned short* xTb = xT + (size_t)b * NTOK * CFULL;

    float bkr[4], bvr[4];
    #pragma unroll
    for (int of = 0; of < 4; ++of) {
        bkr[of] = bk[wv * 64 + of * 16 + l15];
        bvr[of] = bv[wv * 64 + of * 16 + l15];
    }

    f32x16 kvacc0 = {};
    f32x16 kvacc1 = {};
    float ksum[4] = {0.f, 0.f, 0.f, 0.f};

    for (int t = 0; t < ntiles; ++t) {
        const int n0 = (blk * ntiles + t) * TN;
        __syncthreads();              // prev tile fully consumed
        if (use_xT) stage_tile(xTb, n0, xs, wv, lane);
        else        stage_x(xb, n0, xs, wv, lane);
        __syncthreads();

        // ---- K projection (D[tok][och]) + softplus -> ks
        {
            f32x4 acc[4][4] = {};
            #pragma unroll
            for (int kk = 0; kk < 8; ++kk) {
                const int ch0 = kk * 32 + lhi * 8;
                bf16x8 af[4], bfr[4];
                #pragma unroll
                for (int tf = 0; tf < 4; ++tf) {
                    const int tok = tf * 16 + l15;
                    af[tf] = *(const bf16x8*)&xs[tok * CFULL + (ch0 ^ SWZ(tok))];
                }
                #pragma unroll
                for (int of = 0; of < 4; ++of) {
                    const int och = wv * 64 + of * 16 + l15;
                    bfr[of] = *(const bf16x8*)&Wk[och * CFULL + ch0];
                }
                #pragma unroll
                for (int tf = 0; tf < 4; ++tf)
                    #pragma unroll
                    for (int of = 0; of < 4; ++of)
                        acc[tf][of] = __builtin_amdgcn_mfma_f32_16x16x32_bf16(af[tf], bfr[of], acc[tf][of], 0, 0, 0);
            }
            #pragma unroll
            for (int tf = 0; tf < 4; ++tf) {
                #pragma unroll
                for (int of = 0; of < 4; ++of) {
                    const int och = wv * 64 + of * 16 + l15;
                    const float bias = bkr[of];
                    float v0 = softplus_f(acc[tf][of][0] + bias);
                    float v1 = softplus_f(acc[tf][of][1] + bias);
                    float v2 = softplus_f(acc[tf][of][2] + bias);
                    float v3 = softplus_f(acc[tf][of][3] + bias);
                    ksum[of] += v0 + v1 + v2 + v3;
                    ushort4 pk;
                    pk.x = bf16bits(v0); pk.y = bf16bits(v1);
                    pk.z = bf16bits(v2); pk.w = bf16bits(v3);
                    const int tok0 = tf * 16 + lhi * 4;
                    *(ushort4*)&ks[och * TN + (tok0 ^ ((och & 7) << 3))] = pk;
                }
            }
        }

        // ---- V projection (D[tok][och]), packed in registers
        ushort4 vpk[4][4];
        {
            f32x4 acc[4][4] = {};
            #pragma unroll
            for (int kk = 0; kk < 8; ++kk) {
                const int ch0 = kk * 32 + lhi * 8;
                bf16x8 af[4], bfr[4];
                #pragma unroll
                for (int tf = 0; tf < 4; ++tf) {
                    const int tok = tf * 16 + l15;
                    af[tf] = *(const bf16x8*)&xs[tok * CFULL + (ch0 ^ SWZ(tok))];
                }
                #pragma unroll
                for (int of = 0; of < 4; ++of) {
                    const int och = wv * 64 + of * 16 + l15;
                    bfr[of] = *(const bf16x8*)&Wv[och * CFULL + ch0];
                }
                #pragma unroll
                for (int tf = 0; tf < 4; ++tf)
                    #pragma unroll
                    for (int of = 0; of < 4; ++of)
                        acc[tf][of] = __builtin_amdgcn_mfma_f32_16x16x32_bf16(af[tf], bfr[of], acc[tf][of], 0, 0, 0);
            }
            #pragma unroll
            for (int tf = 0; tf < 4; ++tf) {
                #pragma unroll
                for (int of = 0; of < 4; ++of) {
                    const float bias = bvr[of];
                    vpk[tf][of].x = bf16bits(acc[tf][of][0] + bias);
                    vpk[tf][of].y = bf16bits(acc[tf][of][1] + bias);
                    vpk[tf][of].z = bf16bits(acc[tf][of][2] + bias);
                    vpk[tf][of].w = bf16bits(acc[tf][of][3] + bias);
                }
            }
        }
        __syncthreads();              // everyone done reading xs
        #pragma unroll
        for (int tf = 0; tf < 4; ++tf)
            #pragma unroll
            for (int of = 0; of < 4; ++of) {
                const int och = wv * 64 + of * 16 + l15;
                const int tok0 = tf * 16 + lhi * 4;
                *(ushort4*)&xs[och * TN + (tok0 ^ ((och & 7) << 3))] = vpk[tf][of];
            }
        __syncthreads();

        // ---- kv accumulation (wave-local rows of ks/vs)
        {
            const int l31 = lane & 31;
            const int tb = (lane >> 5) * 8;
            #pragma unroll
            for (int h = 0; h < 2; ++h) {
                const int row = (wv * 2 + h) * CH + l31;
                f32x16& kva = h ? kvacc1 : kvacc0;
                #pragma unroll
                for (int ts = 0; ts < 4; ++ts) {
                    const int sw = (ts * 16 + tb) ^ ((row & 7) << 3);
                    bf16x8 ak = *(const bf16x8*)&ks[row * TN + sw];
                    bf16x8 av = *(const bf16x8*)&xs[row * TN + sw];
                    kva = __builtin_amdgcn_mfma_f32_32x32x16_bf16(ak, av, kva, 0, 0, 0);
                }
            }
        }
    }

    // ---- epilogue: coalesced partial stores (no atomics)
    #pragma unroll
    for (int of = 0; of < 4; ++of) {
        float v = ksum[of];
        v += __shfl_xor(v, 16);
        v += __shfl_xor(v, 32);
        if (lhi == 0) kspart[bid * CFULL + wv * 64 + of * 16 + l15] = v;
    }
    {
        float* kvp = kvpart + ((size_t)bid << 13);
        const int l31 = lane & 31;
        const int hi = lane >> 5;
        #pragma unroll
        for (int h = 0; h < 2; ++h) {
            const int p = wv * 2 + h;
            const f32x16& kva = h ? kvacc1 : kvacc0;
            #pragma unroll
            for (int q = 0; q < 4; ++q) {
                const int m0 = 8 * q + 4 * hi;
                f32x4 s;
                s[0] = kva[4 * q + 0]; s[1] = kva[4 * q + 1];
                s[2] = kva[4 * q + 2]; s[3] = kva[4 * q + 3];
                *(f32x4*)&kvp[p * 1024 + l31 * 32 + m0] = s;  // [p][c][m]
            }
        }
    }
}

// ---------------------------------------------------------------------------
// Reduce partials: kvT[b][p][c][m] (bf16), kse[b][ch] = ksum + EPS (f32)
// ---------------------------------------------------------------------------
__global__ __launch_bounds__(256)
void k1r(const float* __restrict__ kvpart, const float* __restrict__ kspart,
         unsigned short* __restrict__ kvT, float* __restrict__ kse, int bpb)
{
    const int o = blockIdx.x * 256 + threadIdx.x;   // 0..65535
    const int b = o >> 13;
    const int r = o & 8191;
    float s = 0.f;
    for (int j = 0; j < bpb; ++j)
        s += kvpart[((size_t)(b * bpb + j) << 13) + r];
    kvT[o] = bf16bits(s);
    if (blockIdx.x < BATCH) {
        const int bb = blockIdx.x;
        float t = 0.f;
        for (int j = 0; j < bpb; ++j)
            t += kspart[(bb * bpb + j) * CFULL + threadIdx.x];
        kse[bb * CFULL + threadIdx.x] = t + EPS;
    }
}

// ---------------------------------------------------------------------------
// Kernel 2: q = softplus(Wq x + bq); out[c,n] = sum_m kv[m,c] q[m,n] / (q.(kse))
// ---------------------------------------------------------------------------
__global__ __launch_bounds__(256, 4)
void k2_out(const float* __restrict__ x, const unsigned short* __restrict__ xT,
            const unsigned short* __restrict__ Wq,
            const float* __restrict__ bq,
            const unsigned short* __restrict__ kvT, const float* __restrict__ ksef,
            float* __restrict__ outp, int use_xT)
{
    __shared__ __align__(16) unsigned short xs[TN * CFULL]; // staged x; later qs[tok][och]
    __shared__ float kse[CFULL];
    __shared__ float bql[CFULL];
    __shared__ float normls[HEADS][TN];

    const int tid = threadIdx.x;
    const int lane = tid & 63;
    const int wv = tid >> 6;
    const int l15 = lane & 15;
    const int lhi = lane >> 4;
    const int b = blockIdx.x >> 8;
    const int blk = blockIdx.x & 255;
    const int n0 = blk * TN;
    float* ob = outp + (size_t)b * CFULL * NTOK;

    bql[tid] = bq[tid];
    kse[tid] = ksef[b * CFULL + tid];

    if (use_xT) stage_tile(xT + (size_t)b * NTOK * CFULL, n0, xs, wv, lane);
    else        stage_x(x + (size_t)b * CFULL * NTOK, n0, xs, wv, lane);
    __syncthreads();

    // ---- Q projection (D[och][tok])
    ushort4 qpk[4][4];
    {
        f32x4 acc[4][4] = {};
        #pragma unroll
        for (int kk = 0; kk < 8; ++kk) {
            const int ch0 = kk * 32 + lhi * 8;
            bf16x8 aw[4], bx[4];
            #pragma unroll
            for (int mf = 0; mf < 4; ++mf)
                aw[mf] = *(const bf16x8*)&Wq[(wv * 64 + mf * 16 + l15) * CFULL + ch0];
            #pragma unroll
            for (int nf = 0; nf < 4; ++nf) {
                const int tok = nf * 16 + l15;
                bx[nf] = *(const bf16x8*)&xs[tok * CFULL + (ch0 ^ SWZ(tok))];
            }
            #pragma unroll
            for (int mf = 0; mf < 4; ++mf)
                #pragma unroll
                for (int nf = 0; nf < 4; ++nf)
                    acc[mf][nf] = __builtin_amdgcn_mfma_f32_16x16x32_bf16(aw[mf], bx[nf], acc[mf][nf], 0, 0, 0);
        }
        #pragma unroll
        for (int mf = 0; mf < 4; ++mf) {
            #pragma unroll
            for (int nf = 0; nf < 4; ++nf) {
                const int och0 = wv * 64 + mf * 16 + lhi * 4;
                qpk[mf][nf].x = bf16bits(softplus_f(acc[mf][nf][0] + bql[och0 + 0]));
                qpk[mf][nf].y = bf16bits(softplus_f(acc[mf][nf][1] + bql[och0 + 1]));
                qpk[mf][nf].z = bf16bits(softplus_f(acc[mf][nf][2] + bql[och0 + 2]));
                qpk[mf][nf].w = bf16bits(softplus_f(acc[mf][nf][3] + bql[och0 + 3]));
            }
        }
    }
    __syncthreads();              // everyone done reading xs
    #pragma unroll
    for (int mf = 0; mf < 4; ++mf)
        #pragma unroll
        for (int nf = 0; nf < 4; ++nf) {
            const int tok = nf * 16 + l15;
            const int och0 = wv * 64 + mf * 16 + lhi * 4;
            *(ushort4*)&xs[tok * CFULL + (och0 ^ SWZ(tok))] = qpk[mf][nf];
        }
    __syncthreads();

    // ---- denominators (wave-local: heads 2wv, 2wv+1)
    #pragma unroll
    for (int h = 0; h < 2; ++h) {
        const int p = wv * 2 + h;
        float d = 0.f;
        #pragma unroll
        for (int mg = 0; mg < 4; ++mg) {
            bf16x8 qv = *(const bf16x8*)&xs[lane * CFULL + ((p * 32 + mg * 8) ^ SWZ(lane))];
            #pragma unroll
            for (int j = 0; j < 8; ++j)
                d += (float)qv[j] * kse[p * 32 + mg * 8 + j];
        }
        normls[p][lane] = 1.0f / d;
    }

    // ---- kv B-fragments (bf16, vectorized from kvT[b][p][c][m])
    bf16x8 bh[2][2];
    #pragma unroll
    for (int h = 0; h < 2; ++h) {
        const int base = (b * HEADS + wv * 2 + h) << 10;
        #pragma unroll
        for (int hf = 0; hf < 2; ++hf)
            bh[h][hf] = *(const bf16x8*)&kvT[base + (hf * 16 + l15) * 32 + lhi * 8];
    }
    __syncthreads();

    // ---- PV: D[tok][c] = sum_m q[m][tok] kv[m][c]; scale by norm; nt float4 stores
    #pragma unroll
    for (int h = 0; h < 2; ++h) {
        const int p = wv * 2 + h;
        #pragma unroll
        for (int nf = 0; nf < 4; ++nf) {
            const int tok = nf * 16 + l15;
            bf16x8 af = *(const bf16x8*)&xs[tok * CFULL + ((p * 32 + lhi * 8) ^ SWZ(tok))];
            f32x4 oA = {}, oB = {};
            oA = __builtin_amdgcn_mfma_f32_16x16x32_bf16(af, bh[h][0], oA, 0, 0, 0);
            oB = __builtin_amdgcn_mfma_f32_16x16x32_bf16(af, bh[h][1], oB, 0, 0, 0);
            const int tb = nf * 16 + lhi * 4;
            f32x4 sA, sB;
            sA[0] = oA[0] * normls[p][tb + 0]; sA[1] = oA[1] * normls[p][tb + 1];
            sA[2] = oA[2] * normls[p][tb + 2]; sA[3] = oA[3] * normls[p][tb + 3];
            sB[0] = oB[0] * normls[p][tb + 0]; sB[1] = oB[1] * normls[p][tb + 1];
            sB[2] = oB[2] * normls[p][tb + 2]; sB[3] = oB[3] * normls[p][tb + 3];
            __builtin_nontemporal_store(sA, (f32x4*)&ob[(size_t)(p * 32 + l15) * NTOK + n0 + tb]);
            __builtin_nontemporal_store(sB, (f32x4*)&ob[(size_t)(p * 32 + 16 + l15) * NTOK + n0 + tb]);
        }
    }
}

extern "C" void kernel_launch(void* const* d_in, const int* in_sizes, int n_in,
                              void* d_out, int out_size, void* d_ws, size_t ws_size,
                              hipStream_t stream)
{
    const float* x  = (const float*)d_in[0];
    const float* Wq = (const float*)d_in[1];
    const float* bq = (const float*)d_in[2];
    const float* Wk = (const float*)d_in[3];
    const float* bk = (const float*)d_in[4];
    const float* Wv = (const float*)d_in[5];
    const float* bv = (const float*)d_in[6];
    float* out = (float*)d_out;

    unsigned char* ws = (unsigned char*)d_ws;
    unsigned short* wbf = (unsigned short*)ws;                    // 384 KB
    unsigned short* kvT = (unsigned short*)(ws + 393216);         // 128 KB
    float* kse = (float*)(ws + 524288);                           // 8 KB

    const size_t xT_sz = (size_t)BATCH * NTOK * CFULL * 2;        // 64 MB

    int bpb = 64, use_xT = 1;
    size_t ksp_off = 532480;
    size_t kvp_off = ksp_off + (size_t)BATCH * bpb * CFULL * 4;
    size_t kvp_sz  = (size_t)BATCH * bpb * 8192 * 4;
    if (ws_size < kvp_off + kvp_sz + xT_sz) {
        // try compact partials
        bpb = 16;
        kvp_off = ksp_off + (size_t)BATCH * bpb * CFULL * 4;
        kvp_sz  = (size_t)BATCH * bpb * 8192 * 4;
        if (ws_size < kvp_off + kvp_sz + xT_sz) {
            use_xT = 0;                                           // no room for xT
            bpb = (ws_size >= ksp_off + (size_t)BATCH * 64 * CFULL * 4 +
                              (size_t)BATCH * 64 * 8192 * 4) ? 64 : 16;
            kvp_off = ksp_off + (size_t)BATCH * bpb * CFULL * 4;
        }
    }
    float* kspart = (float*)(ws + ksp_off);
    float* kvpart = (float*)(ws + kvp_off);
    unsigned short* xT = use_xT ? (unsigned short*)(ws + kvp_off + kvp_sz) : wbf;
    const int ntiles = NTOK / TN / bpb;

    hipLaunchKernelGGL(prep_w, dim3(768), dim3(256), 0, stream, Wq, Wk, Wv, wbf);
    if (use_xT)
        hipLaunchKernelGGL(xpose, dim3(BATCH * 256), dim3(256), 0, stream, x, xT);
    hipLaunchKernelGGL(k1_kv, dim3(BATCH * bpb), dim3(256), 0, stream,
                       x, xT, wbf + 65536, wbf + 2 * 65536, bk, bv,
                       kvpart, kspart, bpb, ntiles, use_xT);
    hipLaunchKernelGGL(k1r, dim3(256), dim3(256), 0, stream,
                       kvpart, kspart, kvT, kse, bpb);
    hipLaunchKernelGGL(k2_out, dim3(BATCH * 256), dim3(256), 0, stream,
                       x, xT, wbf, bq, kvT, kse, out, use_xT);
}